// Round 1
// baseline (36472.028 us; speedup 1.0000x reference)
//
#include <hip/hip_runtime.h>

// BiLSTM-CRF tagger. V=100000 E=300 H=512 C=40 T=4096. ALL I/O float32.
// r7: lstm_phase_k restructured to ZERO barriers per step.
//   - Every wave polls the ENTIRE 512-float h vector itself (64 lanes x 32B
//     chunks, incl. own-wg chunks) into a wave-PRIVATE LDS slice; within-wave
//     lgkmcnt ordering replaces __syncthreads.
//   - Lane layout (hsub x2, gate x4, seg x8): each lane owns a 64-wide slice
//     of one gate row; 3x shfl_xor seg-reduce + 4x shfl gate-gather; activation
//     computed redundantly by all 32 lanes of an h-group; h stored IMMEDIATELY
//     by lanes 0/32 (was: funneled through wave0 after a 2nd barrier).
//   - Removes: 2 barriers/step, lds_g round-trip, wave0 act serialization.
// Sync scheme (r4/r5/r6, proven): h words self-validate —
//   phase 0 stored plain (valid iff != 0xAAAAAAAA ws poison);
//   phase 1 stored with exponent flipped (^0x7F800000): |h|<1 => enc exp>=128,
//   distinguishable from poison (exp 85) and stale layer-0 values (exp<=127).
//   Locations are write-once per phase => per-wave timestep drift is safe.

typedef unsigned int u32;
typedef unsigned long long u64;
typedef u32 u32x4 __attribute__((ext_vector_type(4)));

#define TT 4096
#define HH 512
#define CC 40
#define NG 2048  // 4*H gate rows

__device__ __forceinline__ float sigm(float x) { return 1.0f / (1.0f + __expf(-x)); }
__device__ __forceinline__ float tanh_(float x) { return 1.0f - 2.0f / (__expf(2.0f * x) + 1.0f); }

__device__ __forceinline__ void st_agent_u32(u32* p, u32 v) {
    __hip_atomic_store(p, v, __ATOMIC_RELAXED, __HIP_MEMORY_SCOPE_AGENT);
}

// 32B system-scope-fresh load (bypass L1+L2, read at MALL). Non-atomic: plain
// read path, no atomic-pipe serialization. waitcnt inside: compiler doesn't
// track asm load results.
__device__ __forceinline__ void ld_mall_b256(const float* p, u32x4& r0, u32x4& r1) {
    asm volatile(
        "global_load_dwordx4 %0, %2, off sc0 sc1\n\t"
        "global_load_dwordx4 %1, %2, off offset:16 sc0 sc1\n\t"
        "s_waitcnt vmcnt(0)"
        : "=&v"(r0), "=&v"(r1)
        : "v"(p)
        : "memory");
}

// ---------------- f32 GEMM: C[M,N] = A @ W^T + bias ----------------
// A row m: xidx ? emb[xidx[m]] (K cols) : concat(A0[m](Ksplit), A1[m](K-Ksplit)).
// 128x128 tile, 256 threads, 8x8 micro split as (4+4)x(4+4) halves 64 apart
// (keeps all LDS reads broadcast or 2-way). BK=8 panels, reg-prefetched staging.
__global__ __launch_bounds__(256, 2) void gemm_f32_k(const float* __restrict__ A0,
                                                     const float* __restrict__ A1,
                                                     const int* __restrict__ xidx,
                                                     const float* __restrict__ W,
                                                     const float* __restrict__ bias,
                                                     float* __restrict__ C,
                                                     int M, int N, int K, int Ksplit) {
    __shared__ float sA[8][132];
    __shared__ float sW[8][132];
    int tid = threadIdx.x;
    int bn = blockIdx.x, bm = blockIdx.y;
    int tx = tid & 15, ty = tid >> 4;
    int srow = tid >> 1, skh = (tid & 1) * 4;  // staging: row 0..127, k-half 0/4

    int am = bm * 128 + srow;
    const float* arow0;
    const float* arow1 = nullptr;
    if (xidx) {
        arow0 = A0 + (size_t)xidx[am] * K;
    } else {
        arow0 = A0 + (size_t)am * Ksplit;
        arow1 = A1 + (size_t)am * Ksplit;
    }
    const float* wrow = W + (size_t)(bn * 128 + srow) * K;

    float acc[2][2][4][4] = {};  // [mhalf][nhalf][mi][ni]

    for (int kc = 0; kc < K; kc += 8) {
        float4 av, wv;
        int k0 = kc + skh;
        if (kc + 8 <= K) {
            if (xidx || k0 + 4 <= Ksplit) av = *(const float4*)(arow0 + k0);
            else                          av = *(const float4*)(arow1 + (k0 - Ksplit));
            wv = *(const float4*)(wrow + k0);
        } else {  // K tail (K=300): per-element mask
            float a_[4], w_[4];
#pragma unroll
            for (int j = 0; j < 4; j++) {
                int k = k0 + j;
                bool ok = k < K;
                a_[j] = ok ? ((xidx || k < Ksplit) ? arow0[k] : arow1[k - Ksplit]) : 0.f;
                w_[j] = ok ? wrow[k] : 0.f;
            }
            av = make_float4(a_[0], a_[1], a_[2], a_[3]);
            wv = make_float4(w_[0], w_[1], w_[2], w_[3]);
        }
        __syncthreads();
        sA[skh + 0][srow] = av.x; sA[skh + 1][srow] = av.y;
        sA[skh + 2][srow] = av.z; sA[skh + 3][srow] = av.w;
        sW[skh + 0][srow] = wv.x; sW[skh + 1][srow] = wv.y;
        sW[skh + 2][srow] = wv.z; sW[skh + 3][srow] = wv.w;
        __syncthreads();
#pragma unroll
        for (int k = 0; k < 8; k++) {
            float4 a0 = *(const float4*)&sA[k][ty * 4];
            float4 a1 = *(const float4*)&sA[k][64 + ty * 4];
            float4 w0 = *(const float4*)&sW[k][tx * 4];
            float4 w1 = *(const float4*)&sW[k][64 + tx * 4];
            float am_[2][4] = {{a0.x, a0.y, a0.z, a0.w}, {a1.x, a1.y, a1.z, a1.w}};
            float wn_[2][4] = {{w0.x, w0.y, w0.z, w0.w}, {w1.x, w1.y, w1.z, w1.w}};
#pragma unroll
            for (int p = 0; p < 2; p++)
#pragma unroll
                for (int q = 0; q < 2; q++)
#pragma unroll
                    for (int mi = 0; mi < 4; mi++)
#pragma unroll
                        for (int ni = 0; ni < 4; ni++)
                            acc[p][q][mi][ni] += am_[p][mi] * wn_[q][ni];
        }
    }

#pragma unroll
    for (int q = 0; q < 2; q++) {
        int gn = bn * 128 + q * 64 + tx * 4;
        float4 b4 = *(const float4*)&bias[gn];
#pragma unroll
        for (int p = 0; p < 2; p++) {
            int gm = bm * 128 + p * 64 + ty * 4;
#pragma unroll
            for (int mi = 0; mi < 4; mi++) {
                float4 o;
                o.x = acc[p][q][mi][0] + b4.x; o.y = acc[p][q][mi][1] + b4.y;
                o.z = acc[p][q][mi][2] + b4.z; o.w = acc[p][q][mi][3] + b4.w;
                *(float4*)&C[(size_t)(gm + mi) * N + gn] = o;
            }
        }
    }
}

// ---------------- LSTM recurrent phase (r7: barrier-free) ----------------
// 64 blocks x 512 threads: dir = blk>>5, wg = blk&31 owns h[wg*16..+16).
// Each wave (wid 0..7) computes h indices {wg*16+wid*2, +1}.
// Lane l: hsub=l>>5, gate=(l>>3)&3, seg=l&7. Gate row grow = gate*512+hidx,
// k-slice [seg*64,+64): 64 Whh weights/thread in VGPRs.
// Per step: every lane polls h-chunk l (32B) of the previous timestep from
// MALL, drops it decoded into the wave's PRIVATE LDS slice, dot over own
// k-slice, shfl_xor(1,2,4) seg-reduce, shfl gate-gather, activation in all
// lanes of the h-group, lanes 0/32 store h (agent scope). No __syncthreads.
__global__ __attribute__((amdgpu_flat_work_group_size(512, 512), amdgpu_waves_per_eu(2, 2)))
void lstm_phase_k(const float* __restrict__ WxF,
                  const float* __restrict__ WxB,
                  const float* __restrict__ WhhF,
                  const float* __restrict__ WhhB,
                  float* __restrict__ histF,
                  float* __restrict__ histB,
                  int phase) {
    const int wg = blockIdx.x & 31;
    const int dir = blockIdx.x >> 5;
    const int tid = threadIdx.x;
    const int wid = tid >> 6;
    const int lane = tid & 63;
    const int hsub = lane >> 5;
    const int gate = (lane >> 3) & 3;
    const int seg = lane & 7;
    const float* Wx = dir ? WxB : WxF;
    const float* Whh = dir ? WhhB : WhhF;
    float* hist = dir ? histB : histF;
    const u32 ENC = phase ? 0x7F800000u : 0u;

    const int hidx = wg * 16 + wid * 2 + hsub;  // h index this lane's group computes
    const int grow = gate * 512 + hidx;         // gate row in [0,2048)

    float w[64];
    {
        const float* wr = Whh + (size_t)grow * HH + seg * 64;
#pragma unroll
        for (int i = 0; i < 16; i++) {
            float4 v = *(const float4*)(wr + i * 4);
            w[i * 4 + 0] = v.x; w[i * 4 + 1] = v.y; w[i * 4 + 2] = v.z; w[i * 4 + 3] = v.w;
        }
    }

    // wave-private h copies: 8 seg-chunks of 64 floats, stride 68 (bank-spread)
    __shared__ float lds_h[8][8 * 68];
    float* myl = &lds_h[wid][0];
    // this lane's LDS drop slot for polled chunk `lane` (h[8*lane .. +8))
    float* dst = myl + (lane >> 3) * 68 + (lane & 7) * 8;

    float c_state = 0.f;
    int capped = 0;

    for (int s = 0; s < TT; ++s) {
        const int t = dir ? (TT - 1 - s) : s;
        float wxv = 0.f;
        if (seg == 0) wxv = Wx[(size_t)t * NG + grow];  // prefetch, hidden behind poll

        float dot = 0.f;
        if (s > 0) {
            const int tprev = dir ? (t + 1) : (t - 1);
            const float* p = hist + (size_t)tprev * HH + lane * 8;
            u32x4 v0, v1;
            if (!capped) {
                int it = 0;
                for (;;) {
                    ld_mall_b256(p, v0, v1);
                    bool ok;
                    if (phase) {
                        ok = ((v0.x & 0x7F800000u) >= 0x40000000u) &&
                             ((v0.y & 0x7F800000u) >= 0x40000000u) &&
                             ((v0.z & 0x7F800000u) >= 0x40000000u) &&
                             ((v0.w & 0x7F800000u) >= 0x40000000u) &&
                             ((v1.x & 0x7F800000u) >= 0x40000000u) &&
                             ((v1.y & 0x7F800000u) >= 0x40000000u) &&
                             ((v1.z & 0x7F800000u) >= 0x40000000u) &&
                             ((v1.w & 0x7F800000u) >= 0x40000000u);
                    } else {
                        ok = (v0.x != 0xAAAAAAAAu) && (v0.y != 0xAAAAAAAAu) &&
                             (v0.z != 0xAAAAAAAAu) && (v0.w != 0xAAAAAAAAu) &&
                             (v1.x != 0xAAAAAAAAu) && (v1.y != 0xAAAAAAAAu) &&
                             (v1.z != 0xAAAAAAAAu) && (v1.w != 0xAAAAAAAAu);
                    }
                    if (ok) break;
                    if (++it > (1 << 18)) { capped = 1; break; }  // sticky: never hang
                }
            } else {
                ld_mall_b256(p, v0, v1);
            }
            float4 f0, f1;
            f0.x = __uint_as_float(v0.x ^ ENC); f0.y = __uint_as_float(v0.y ^ ENC);
            f0.z = __uint_as_float(v0.z ^ ENC); f0.w = __uint_as_float(v0.w ^ ENC);
            f1.x = __uint_as_float(v1.x ^ ENC); f1.y = __uint_as_float(v1.y ^ ENC);
            f1.z = __uint_as_float(v1.z ^ ENC); f1.w = __uint_as_float(v1.w ^ ENC);
            *(float4*)dst = f0;
            *(float4*)(dst + 4) = f1;
            // wave-local LDS: compiler's lgkmcnt before the reads orders this;
            // DS ops are in-order per wave, so next iter's writes can't pass
            // this iter's reads. No barrier needed.
            float a0 = 0.f, a1 = 0.f, a2 = 0.f, a3 = 0.f;
            const float4* hv4 = (const float4*)(myl + seg * 68);
#pragma unroll
            for (int i = 0; i < 16; i++) {
                float4 hv = hv4[i];
                a0 += w[i * 4 + 0] * hv.x;
                a1 += w[i * 4 + 1] * hv.y;
                a2 += w[i * 4 + 2] * hv.z;
                a3 += w[i * 4 + 3] * hv.w;
            }
            dot = (a0 + a1) + (a2 + a3);
        }

        float acc = dot + wxv;  // wxv nonzero only at seg==0 => counted once in reduce
        acc += __shfl_xor(acc, 1);
        acc += __shfl_xor(acc, 2);
        acc += __shfl_xor(acc, 4);
        // gather the 4 gate values of this lane's h-group
        const int base = (lane & 32) + seg;
        float gi = __shfl(acc, base + 0);
        float gf = __shfl(acc, base + 8);
        float gg = __shfl(acc, base + 16);
        float go = __shfl(acc, base + 24);
        float iv = sigm(gi), fv = sigm(gf), gv = tanh_(gg), ov = sigm(go);
        c_state = fv * c_state + iv * gv;
        float h = ov * tanh_(c_state);
        if ((lane & 31) == 0)  // one store per h-group (lanes 0 and 32)
            st_agent_u32((u32*)&hist[(size_t)t * HH + hidx], __float_as_uint(h) ^ ENC);
    }
}

// ---------------- classifier + log_softmax (writes scores to d_out) ----------------
// hist holds phase-1 encoding: decode = xor 0x7F800000 per word.
__global__ __launch_bounds__(64, 4) void classifier_k(const float* __restrict__ histF,
                                                      const float* __restrict__ histB,
                                                      const float* __restrict__ Wc,
                                                      const float* __restrict__ bc,
                                                      float* __restrict__ outsc) {
    int t = blockIdx.x, lane = threadIdx.x;
    __shared__ float hrow[1024];
    const uint4* hf4 = (const uint4*)(histF + (size_t)t * HH);
    const uint4* hb4 = (const uint4*)(histB + (size_t)t * HH);
#pragma unroll
    for (int jj = 0; jj < 4; jj++) {
        int idx4 = jj * 64 + lane;  // 0..255 uint4s
        uint4 u = (idx4 < 128) ? hf4[idx4] : hb4[idx4 - 128];
        u.x ^= 0x7F800000u; u.y ^= 0x7F800000u; u.z ^= 0x7F800000u; u.w ^= 0x7F800000u;
        float4 v;
        v.x = __uint_as_float(u.x); v.y = __uint_as_float(u.y);
        v.z = __uint_as_float(u.z); v.w = __uint_as_float(u.w);
        *(float4*)&hrow[idx4 * 4] = v;
    }
    __syncthreads();
    float o = 0.f;
    if (lane < CC) {
        o = bc[lane];
        const float4* wr = (const float4*)(Wc + (size_t)lane * 1024);
#pragma unroll 4
        for (int kk = 0; kk < 256; ++kk) {
            float4 w4 = wr[kk];
            float4 h4 = *(const float4*)&hrow[kk * 4];
            o += w4.x * h4.x + w4.y * h4.y + w4.z * h4.z + w4.w * h4.w;
        }
    }
    float m = (lane < CC) ? o : -1e30f;
#pragma unroll
    for (int d = 1; d < 64; d <<= 1) m = fmaxf(m, __shfl_xor(m, d));
    float ex = (lane < CC) ? __expf(o - m) : 0.f;
#pragma unroll
    for (int d = 1; d < 64; d <<= 1) ex += __shfl_xor(ex, d);
    float lse = m + __logf(ex);
    if (lane < CC) outsc[(size_t)t * CC + lane] = o - lse;
}

// ---------------- viterbi forward + backtrack (single wave, shfl broadcast) ----------------
__global__ __launch_bounds__(64) void viterbi_k(const float* __restrict__ em,
                                               const float* __restrict__ trans,
                                               const float* __restrict__ startv,
                                               const float* __restrict__ endv,
                                               unsigned char* __restrict__ bp,
                                               float* __restrict__ outtags) {
    int lane = threadIdx.x;
    float tcol[CC];
#pragma unroll
    for (int p = 0; p < CC; p++) tcol[p] = 0.f;
    if (lane < CC) {
#pragma unroll
        for (int p = 0; p < CC; p++) tcol[p] = trans[p * CC + lane];  // trans[prev][next=lane]
    }
    float s = (lane < CC) ? (startv[lane] + em[lane]) : 0.f;

    for (int t = 1; t < TT; ++t) {
        float emv = (lane < CC) ? em[(size_t)t * CC + lane] : 0.f;
        float b0 = -1e30f, b1 = -1e30f;
        int i0 = 0, i1 = 20;
#pragma unroll
        for (int p = 0; p < 20; p++) {
            float c0 = __shfl(s, p) + tcol[p];
            float c1 = __shfl(s, p + 20) + tcol[p + 20];
            if (c0 > b0) { b0 = c0; i0 = p; }       // strict > = first-max
            if (c1 > b1) { b1 = c1; i1 = p + 20; }
        }
        float best = b0; int bi = i0;
        if (b1 > b0) { best = b1; bi = i1; }        // tie -> lower-index chain 0
        s = best + emv;
        if (lane < CC) bp[(size_t)t * CC + lane] = (unsigned char)bi;
    }
    float fv = (lane < CC) ? (s + endv[lane]) : -1e30f;
    int fi = (lane < CC) ? lane : 63;
#pragma unroll
    for (int d = 1; d < 64; d <<= 1) {
        float ov = __shfl_xor(fv, d);
        int oi = __shfl_xor(fi, d);
        if (ov > fv || (ov == fv && oi < fi)) { fv = ov; fi = oi; }
    }
    __threadfence();   // bp stores (lanes 0..39) visible to lane 0's loads
    if (lane == 0) {
        int cur = fi;
        outtags[TT - 1] = (float)cur;
        for (int t = TT - 2; t >= 0; --t) {
            cur = bp[(size_t)(t + 1) * CC + cur];
            outtags[t] = (float)cur;
        }
    }
}

extern "C" void kernel_launch(void* const* d_in, const int* in_sizes, int n_in,
                              void* d_out, int out_size, void* d_ws, size_t ws_size,
                              hipStream_t stream) {
    const int*   x     = (const int*)d_in[0];
    const float* emb   = (const float*)d_in[1];
    const float* Wih0f = (const float*)d_in[2];
    const float* Whh0f = (const float*)d_in[3];
    const float* b0f   = (const float*)d_in[4];
    const float* Wih0b = (const float*)d_in[5];
    const float* Whh0b = (const float*)d_in[6];
    const float* b0b   = (const float*)d_in[7];
    const float* Wih1f = (const float*)d_in[8];
    const float* Whh1f = (const float*)d_in[9];
    const float* b1f   = (const float*)d_in[10];
    const float* Wih1b = (const float*)d_in[11];
    const float* Whh1b = (const float*)d_in[12];
    const float* b1b   = (const float*)d_in[13];
    const float* Wc    = (const float*)d_in[14];
    const float* bc    = (const float*)d_in[15];
    const float* trans = (const float*)d_in[16];
    const float* startv= (const float*)d_in[17];
    const float* endv  = (const float*)d_in[18];

    char* ws = (char*)d_ws;
    // layout, total 84,148,224 B
    unsigned char* bp = (unsigned char*)(ws + 1024);       // 4096*40 = 163,840
    float* WxF  = (float*)(ws + 262144);                   // 4096*2048*4 = 33,554,432
    float* WxB  = (float*)(ws + 33816576);                 // 33,554,432
    float* histF= (float*)(ws + 67371008);                 // 4096*512*4 = 8,388,608
    float* histB= (float*)(ws + 75759616);                 // 8,388,608 -> 84,148,224

    if (ws_size < (size_t)84148224) return;  // diagnostic: zero output => ws too small

    float* out_sc   = (float*)d_out;                 // 4096*40 scores
    float* out_tags = out_sc + (size_t)TT * CC;      // 4096 tags (as float)

    // layer 0 input projections (emb gather fused into GEMM)
    gemm_f32_k<<<dim3(16, 32), 256, 0, stream>>>(emb, nullptr, x, Wih0f, b0f, WxF, TT, NG, 300, 300);
    gemm_f32_k<<<dim3(16, 32), 256, 0, stream>>>(emb, nullptr, x, Wih0b, b0b, WxB, TT, NG, 300, 300);
    lstm_phase_k<<<64, 512, 0, stream>>>(WxF, WxB, Whh0f, Whh0b, histF, histB, 0);
    // layer 1 input projections (A = concat(histF, histB), plain layer-0 bits)
    gemm_f32_k<<<dim3(16, 32), 256, 0, stream>>>(histF, histB, nullptr, Wih1f, b1f, WxF, TT, NG, 1024, 512);
    gemm_f32_k<<<dim3(16, 32), 256, 0, stream>>>(histF, histB, nullptr, Wih1b, b1b, WxB, TT, NG, 1024, 512);
    lstm_phase_k<<<64, 512, 0, stream>>>(WxF, WxB, Whh1f, Whh1b, histF, histB, 1);
    classifier_k<<<TT, 64, 0, stream>>>(histF, histB, Wc, bc, out_sc);
    viterbi_k<<<1, 64, 0, stream>>>(out_sc, trans, startv, endv, bp, out_tags);
}

// Round 2
// 26223.447 us; speedup vs baseline: 1.3908x; 1.3908x over previous
//
#include <hip/hip_runtime.h>

// BiLSTM-CRF tagger. V=100000 E=300 H=512 C=40 T=4096. ALL I/O float32.
// r8 = r6 poll structure + r7 compute structure:
//   - Pollers: tid<62 (wave 0 only) poll 62 remote 32B chunks into ONE shared
//     LDS h-copy (r6-proven traffic level; r7's 8x redundant polling caused
//     fabric contention: FETCH 141->358GB, dur 7.1->17-37ms bimodal).
//   - LDS h-buffer double-buffered by step parity => ONE barrier per step
//     (r6 had two). Own-wg h written into next-parity buffer at store time.
//   - Compute: lane layout (hsub x2, gate x4, seg x8); all 4 gates of an
//     h-pair live in one wave; shfl_xor seg-reduce + shfl gate-gather;
//     activation redundant in all 32 lanes of the h-group; store issued
//     immediately (no lds_g round-trip, no wave0 funnel, no 2nd barrier).
// Sync scheme (r4/r5/r6, proven): h words self-validate —
//   phase 0 stored plain (valid iff != 0xAAAAAAAA ws poison);
//   phase 1 stored with exponent flipped (^0x7F800000): |h|<1 => enc exp>=128,
//   distinguishable from poison (exp 85) and stale layer-0 values (exp<=127).
//   Locations are write-once per phase => per-wave timestep drift is safe.

typedef unsigned int u32;
typedef unsigned long long u64;
typedef u32 u32x4 __attribute__((ext_vector_type(4)));

#define TT 4096
#define HH 512
#define CC 40
#define NG 2048  // 4*H gate rows

__device__ __forceinline__ float sigm(float x) { return 1.0f / (1.0f + __expf(-x)); }
__device__ __forceinline__ float tanh_(float x) { return 1.0f - 2.0f / (__expf(2.0f * x) + 1.0f); }

__device__ __forceinline__ void st_agent_u32(u32* p, u32 v) {
    __hip_atomic_store(p, v, __ATOMIC_RELAXED, __HIP_MEMORY_SCOPE_AGENT);
}

// 32B system-scope-fresh load (bypass L1+L2, read at MALL). Non-atomic: plain
// read path, no atomic-pipe serialization. waitcnt inside: compiler doesn't
// track asm load results.
__device__ __forceinline__ void ld_mall_b256(const float* p, u32x4& r0, u32x4& r1) {
    asm volatile(
        "global_load_dwordx4 %0, %2, off sc0 sc1\n\t"
        "global_load_dwordx4 %1, %2, off offset:16 sc0 sc1\n\t"
        "s_waitcnt vmcnt(0)"
        : "=&v"(r0), "=&v"(r1)
        : "v"(p)
        : "memory");
}

// ---------------- f32 GEMM: C[M,N] = A @ W^T + bias ----------------
// A row m: xidx ? emb[xidx[m]] (K cols) : concat(A0[m](Ksplit), A1[m](K-Ksplit)).
// 128x128 tile, 256 threads, 8x8 micro split as (4+4)x(4+4) halves 64 apart
// (keeps all LDS reads broadcast or 2-way). BK=8 panels, reg-prefetched staging.
__global__ __launch_bounds__(256, 2) void gemm_f32_k(const float* __restrict__ A0,
                                                     const float* __restrict__ A1,
                                                     const int* __restrict__ xidx,
                                                     const float* __restrict__ W,
                                                     const float* __restrict__ bias,
                                                     float* __restrict__ C,
                                                     int M, int N, int K, int Ksplit) {
    __shared__ float sA[8][132];
    __shared__ float sW[8][132];
    int tid = threadIdx.x;
    int bn = blockIdx.x, bm = blockIdx.y;
    int tx = tid & 15, ty = tid >> 4;
    int srow = tid >> 1, skh = (tid & 1) * 4;  // staging: row 0..127, k-half 0/4

    int am = bm * 128 + srow;
    const float* arow0;
    const float* arow1 = nullptr;
    if (xidx) {
        arow0 = A0 + (size_t)xidx[am] * K;
    } else {
        arow0 = A0 + (size_t)am * Ksplit;
        arow1 = A1 + (size_t)am * Ksplit;
    }
    const float* wrow = W + (size_t)(bn * 128 + srow) * K;

    float acc[2][2][4][4] = {};  // [mhalf][nhalf][mi][ni]

    for (int kc = 0; kc < K; kc += 8) {
        float4 av, wv;
        int k0 = kc + skh;
        if (kc + 8 <= K) {
            if (xidx || k0 + 4 <= Ksplit) av = *(const float4*)(arow0 + k0);
            else                          av = *(const float4*)(arow1 + (k0 - Ksplit));
            wv = *(const float4*)(wrow + k0);
        } else {  // K tail (K=300): per-element mask
            float a_[4], w_[4];
#pragma unroll
            for (int j = 0; j < 4; j++) {
                int k = k0 + j;
                bool ok = k < K;
                a_[j] = ok ? ((xidx || k < Ksplit) ? arow0[k] : arow1[k - Ksplit]) : 0.f;
                w_[j] = ok ? wrow[k] : 0.f;
            }
            av = make_float4(a_[0], a_[1], a_[2], a_[3]);
            wv = make_float4(w_[0], w_[1], w_[2], w_[3]);
        }
        __syncthreads();
        sA[skh + 0][srow] = av.x; sA[skh + 1][srow] = av.y;
        sA[skh + 2][srow] = av.z; sA[skh + 3][srow] = av.w;
        sW[skh + 0][srow] = wv.x; sW[skh + 1][srow] = wv.y;
        sW[skh + 2][srow] = wv.z; sW[skh + 3][srow] = wv.w;
        __syncthreads();
#pragma unroll
        for (int k = 0; k < 8; k++) {
            float4 a0 = *(const float4*)&sA[k][ty * 4];
            float4 a1 = *(const float4*)&sA[k][64 + ty * 4];
            float4 w0 = *(const float4*)&sW[k][tx * 4];
            float4 w1 = *(const float4*)&sW[k][64 + tx * 4];
            float am_[2][4] = {{a0.x, a0.y, a0.z, a0.w}, {a1.x, a1.y, a1.z, a1.w}};
            float wn_[2][4] = {{w0.x, w0.y, w0.z, w0.w}, {w1.x, w1.y, w1.z, w1.w}};
#pragma unroll
            for (int p = 0; p < 2; p++)
#pragma unroll
                for (int q = 0; q < 2; q++)
#pragma unroll
                    for (int mi = 0; mi < 4; mi++)
#pragma unroll
                        for (int ni = 0; ni < 4; ni++)
                            acc[p][q][mi][ni] += am_[p][mi] * wn_[q][ni];
        }
    }

#pragma unroll
    for (int q = 0; q < 2; q++) {
        int gn = bn * 128 + q * 64 + tx * 4;
        float4 b4 = *(const float4*)&bias[gn];
#pragma unroll
        for (int p = 0; p < 2; p++) {
            int gm = bm * 128 + p * 64 + ty * 4;
#pragma unroll
            for (int mi = 0; mi < 4; mi++) {
                float4 o;
                o.x = acc[p][q][mi][0] + b4.x; o.y = acc[p][q][mi][1] + b4.y;
                o.z = acc[p][q][mi][2] + b4.z; o.w = acc[p][q][mi][3] + b4.w;
                *(float4*)&C[(size_t)(gm + mi) * N + gn] = o;
            }
        }
    }
}

// ---------------- LSTM recurrent phase (r8) ----------------
// 64 blocks x 512 threads: dir = blk>>5, wg = blk&31 owns h[wg*16..+16).
// Wave wid computes h indices {wg*16 + wid*2 + hsub}, hsub = lane>>5.
// Lane l: gate=(l>>3)&3, seg=l&7. Gate row grow = gate*512 + hidx,
// k-slice [seg*64,+64): 64 Whh weights/thread in VGPRs.
// Per step: tid<62 poll the 62 remote 32B chunks of h(t_prev) from MALL into
// the parity-selected shared LDS buffer; ONE __syncthreads; all waves dot over
// the shared copy; shfl_xor(1,2,4) seg-reduce; shfl gate-gather; activation in
// all lanes of the h-group; lanes 0/32 store h (agent scope) AND drop it into
// the next-parity LDS buffer (own-wg chunks are never polled).
__global__ __attribute__((amdgpu_flat_work_group_size(512, 512), amdgpu_waves_per_eu(2, 2)))
void lstm_phase_k(const float* __restrict__ WxF,
                  const float* __restrict__ WxB,
                  const float* __restrict__ WhhF,
                  const float* __restrict__ WhhB,
                  float* __restrict__ histF,
                  float* __restrict__ histB,
                  int phase) {
    const int wg = blockIdx.x & 31;
    const int dir = blockIdx.x >> 5;
    const int tid = threadIdx.x;
    const int wid = tid >> 6;
    const int lane = tid & 63;
    const int hsub = lane >> 5;
    const int gate = (lane >> 3) & 3;
    const int seg = lane & 7;
    const float* Wx = dir ? WxB : WxF;
    const float* Whh = dir ? WhhB : WhhF;
    float* hist = dir ? histB : histF;
    const u32 ENC = phase ? 0x7F800000u : 0u;

    const int hidx = wg * 16 + wid * 2 + hsub;  // h index this lane's group computes
    const int grow = gate * 512 + hidx;         // gate row in [0,2048)

    float w[64];
    {
        const float* wr = Whh + (size_t)grow * HH + seg * 64;
#pragma unroll
        for (int i = 0; i < 16; i++) {
            float4 v = *(const float4*)(wr + i * 4);
            w[i * 4 + 0] = v.x; w[i * 4 + 1] = v.y; w[i * 4 + 2] = v.z; w[i * 4 + 3] = v.w;
        }
    }

    // 32B-chunk index this thread polls (64 chunks of 8 floats; skip own wg's 2)
    const int j = (tid < 62) ? (tid + (tid >= wg * 2 ? 2 : 0)) : 0;

    // shared h copy, double-buffered by step parity: 8 seg-chunks of 64, stride 68
    __shared__ float lds_h[2][8 * 68];
    const int ownslot = (hidx >> 6) * 68 + (hidx & 63);

    float c_state = 0.f;
    int capped = 0;

    for (int s = 0; s < TT; ++s) {
        const int t = dir ? (TT - 1 - s) : s;
        float wxv = 0.f;
        if (seg == 0) wxv = Wx[(size_t)t * NG + grow];  // prefetch, hidden behind poll

        float dot = 0.f;
        if (s > 0) {
            const int par = s & 1;
            if (tid < 62) {
                const int tprev = dir ? (t + 1) : (t - 1);
                const float* p = hist + (size_t)tprev * HH + j * 8;
                u32x4 v0, v1;
                if (!capped) {
                    int it = 0;
                    for (;;) {
                        ld_mall_b256(p, v0, v1);
                        bool ok;
                        if (phase) {
                            ok = ((v0.x & 0x7F800000u) >= 0x40000000u) &&
                                 ((v0.y & 0x7F800000u) >= 0x40000000u) &&
                                 ((v0.z & 0x7F800000u) >= 0x40000000u) &&
                                 ((v0.w & 0x7F800000u) >= 0x40000000u) &&
                                 ((v1.x & 0x7F800000u) >= 0x40000000u) &&
                                 ((v1.y & 0x7F800000u) >= 0x40000000u) &&
                                 ((v1.z & 0x7F800000u) >= 0x40000000u) &&
                                 ((v1.w & 0x7F800000u) >= 0x40000000u);
                        } else {
                            ok = (v0.x != 0xAAAAAAAAu) && (v0.y != 0xAAAAAAAAu) &&
                                 (v0.z != 0xAAAAAAAAu) && (v0.w != 0xAAAAAAAAu) &&
                                 (v1.x != 0xAAAAAAAAu) && (v1.y != 0xAAAAAAAAu) &&
                                 (v1.z != 0xAAAAAAAAu) && (v1.w != 0xAAAAAAAAu);
                        }
                        if (ok) break;
                        if (++it > (1 << 18)) { capped = 1; break; }  // sticky: never hang
                    }
                } else {
                    ld_mall_b256(p, v0, v1);
                }
                float* dst = &lds_h[par][(j >> 3) * 68 + ((j & 7) * 8)];
                float4 f0, f1;
                f0.x = __uint_as_float(v0.x ^ ENC); f0.y = __uint_as_float(v0.y ^ ENC);
                f0.z = __uint_as_float(v0.z ^ ENC); f0.w = __uint_as_float(v0.w ^ ENC);
                f1.x = __uint_as_float(v1.x ^ ENC); f1.y = __uint_as_float(v1.y ^ ENC);
                f1.z = __uint_as_float(v1.z ^ ENC); f1.w = __uint_as_float(v1.w ^ ENC);
                *(float4*)dst = f0;
                *(float4*)(dst + 4) = f1;
            }
            __syncthreads();  // the ONLY barrier per step
            float a0 = 0.f, a1 = 0.f, a2 = 0.f, a3 = 0.f;
            const float4* hv4 = (const float4*)(&lds_h[par][seg * 68]);
#pragma unroll
            for (int i = 0; i < 16; i++) {
                float4 hv = hv4[i];
                a0 += w[i * 4 + 0] * hv.x;
                a1 += w[i * 4 + 1] * hv.y;
                a2 += w[i * 4 + 2] * hv.z;
                a3 += w[i * 4 + 3] * hv.w;
            }
            dot = (a0 + a1) + (a2 + a3);
        }

        float acc = dot + wxv;  // wxv nonzero only at seg==0 => counted once in reduce
        acc += __shfl_xor(acc, 1);
        acc += __shfl_xor(acc, 2);
        acc += __shfl_xor(acc, 4);
        // gather the 4 gate values of this lane's h-group
        const int base = (lane & 32) + seg;
        float gi = __shfl(acc, base + 0);
        float gf = __shfl(acc, base + 8);
        float gg = __shfl(acc, base + 16);
        float go = __shfl(acc, base + 24);
        float iv = sigm(gi), fv = sigm(gf), gv = tanh_(gg), ov = sigm(go);
        c_state = fv * c_state + iv * gv;
        float h = ov * tanh_(c_state);
        if ((lane & 31) == 0) {  // one store per h-group (lanes 0 and 32)
            lds_h[(s + 1) & 1][ownslot] = h;  // own slice for next step's dot
            st_agent_u32((u32*)&hist[(size_t)t * HH + hidx], __float_as_uint(h) ^ ENC);
        }
        // no end barrier: next step's poll writes go to buf[(s+1)&1], whose
        // iter-(s-1) readers provably drained before this step's barrier.
    }
}

// ---------------- classifier + log_softmax (writes scores to d_out) ----------------
// hist holds phase-1 encoding: decode = xor 0x7F800000 per word.
__global__ __launch_bounds__(64, 4) void classifier_k(const float* __restrict__ histF,
                                                      const float* __restrict__ histB,
                                                      const float* __restrict__ Wc,
                                                      const float* __restrict__ bc,
                                                      float* __restrict__ outsc) {
    int t = blockIdx.x, lane = threadIdx.x;
    __shared__ float hrow[1024];
    const uint4* hf4 = (const uint4*)(histF + (size_t)t * HH);
    const uint4* hb4 = (const uint4*)(histB + (size_t)t * HH);
#pragma unroll
    for (int jj = 0; jj < 4; jj++) {
        int idx4 = jj * 64 + lane;  // 0..255 uint4s
        uint4 u = (idx4 < 128) ? hf4[idx4] : hb4[idx4 - 128];
        u.x ^= 0x7F800000u; u.y ^= 0x7F800000u; u.z ^= 0x7F800000u; u.w ^= 0x7F800000u;
        float4 v;
        v.x = __uint_as_float(u.x); v.y = __uint_as_float(u.y);
        v.z = __uint_as_float(u.z); v.w = __uint_as_float(u.w);
        *(float4*)&hrow[idx4 * 4] = v;
    }
    __syncthreads();
    float o = 0.f;
    if (lane < CC) {
        o = bc[lane];
        const float4* wr = (const float4*)(Wc + (size_t)lane * 1024);
#pragma unroll 4
        for (int kk = 0; kk < 256; ++kk) {
            float4 w4 = wr[kk];
            float4 h4 = *(const float4*)&hrow[kk * 4];
            o += w4.x * h4.x + w4.y * h4.y + w4.z * h4.z + w4.w * h4.w;
        }
    }
    float m = (lane < CC) ? o : -1e30f;
#pragma unroll
    for (int d = 1; d < 64; d <<= 1) m = fmaxf(m, __shfl_xor(m, d));
    float ex = (lane < CC) ? __expf(o - m) : 0.f;
#pragma unroll
    for (int d = 1; d < 64; d <<= 1) ex += __shfl_xor(ex, d);
    float lse = m + __logf(ex);
    if (lane < CC) outsc[(size_t)t * CC + lane] = o - lse;
}

// ---------------- viterbi forward + backtrack (single wave, shfl broadcast) ----------------
__global__ __launch_bounds__(64) void viterbi_k(const float* __restrict__ em,
                                               const float* __restrict__ trans,
                                               const float* __restrict__ startv,
                                               const float* __restrict__ endv,
                                               unsigned char* __restrict__ bp,
                                               float* __restrict__ outtags) {
    int lane = threadIdx.x;
    float tcol[CC];
#pragma unroll
    for (int p = 0; p < CC; p++) tcol[p] = 0.f;
    if (lane < CC) {
#pragma unroll
        for (int p = 0; p < CC; p++) tcol[p] = trans[p * CC + lane];  // trans[prev][next=lane]
    }
    float s = (lane < CC) ? (startv[lane] + em[lane]) : 0.f;

    for (int t = 1; t < TT; ++t) {
        float emv = (lane < CC) ? em[(size_t)t * CC + lane] : 0.f;
        float b0 = -1e30f, b1 = -1e30f;
        int i0 = 0, i1 = 20;
#pragma unroll
        for (int p = 0; p < 20; p++) {
            float c0 = __shfl(s, p) + tcol[p];
            float c1 = __shfl(s, p + 20) + tcol[p + 20];
            if (c0 > b0) { b0 = c0; i0 = p; }       // strict > = first-max
            if (c1 > b1) { b1 = c1; i1 = p + 20; }
        }
        float best = b0; int bi = i0;
        if (b1 > b0) { best = b1; bi = i1; }        // tie -> lower-index chain 0
        s = best + emv;
        if (lane < CC) bp[(size_t)t * CC + lane] = (unsigned char)bi;
    }
    float fv = (lane < CC) ? (s + endv[lane]) : -1e30f;
    int fi = (lane < CC) ? lane : 63;
#pragma unroll
    for (int d = 1; d < 64; d <<= 1) {
        float ov = __shfl_xor(fv, d);
        int oi = __shfl_xor(fi, d);
        if (ov > fv || (ov == fv && oi < fi)) { fv = ov; fi = oi; }
    }
    __threadfence();   // bp stores (lanes 0..39) visible to lane 0's loads
    if (lane == 0) {
        int cur = fi;
        outtags[TT - 1] = (float)cur;
        for (int t = TT - 2; t >= 0; --t) {
            cur = bp[(size_t)(t + 1) * CC + cur];
            outtags[t] = (float)cur;
        }
    }
}

extern "C" void kernel_launch(void* const* d_in, const int* in_sizes, int n_in,
                              void* d_out, int out_size, void* d_ws, size_t ws_size,
                              hipStream_t stream) {
    const int*   x     = (const int*)d_in[0];
    const float* emb   = (const float*)d_in[1];
    const float* Wih0f = (const float*)d_in[2];
    const float* Whh0f = (const float*)d_in[3];
    const float* b0f   = (const float*)d_in[4];
    const float* Wih0b = (const float*)d_in[5];
    const float* Whh0b = (const float*)d_in[6];
    const float* b0b   = (const float*)d_in[7];
    const float* Wih1f = (const float*)d_in[8];
    const float* Whh1f = (const float*)d_in[9];
    const float* b1f   = (const float*)d_in[10];
    const float* Wih1b = (const float*)d_in[11];
    const float* Whh1b = (const float*)d_in[12];
    const float* b1b   = (const float*)d_in[13];
    const float* Wc    = (const float*)d_in[14];
    const float* bc    = (const float*)d_in[15];
    const float* trans = (const float*)d_in[16];
    const float* startv= (const float*)d_in[17];
    const float* endv  = (const float*)d_in[18];

    char* ws = (char*)d_ws;
    // layout, total 84,148,224 B
    unsigned char* bp = (unsigned char*)(ws + 1024);       // 4096*40 = 163,840
    float* WxF  = (float*)(ws + 262144);                   // 4096*2048*4 = 33,554,432
    float* WxB  = (float*)(ws + 33816576);                 // 33,554,432
    float* histF= (float*)(ws + 67371008);                 // 4096*512*4 = 8,388,608
    float* histB= (float*)(ws + 75759616);                 // 8,388,608 -> 84,148,224

    if (ws_size < (size_t)84148224) return;  // diagnostic: zero output => ws too small

    float* out_sc   = (float*)d_out;                 // 4096*40 scores
    float* out_tags = out_sc + (size_t)TT * CC;      // 4096 tags (as float)

    // layer 0 input projections (emb gather fused into GEMM)
    gemm_f32_k<<<dim3(16, 32), 256, 0, stream>>>(emb, nullptr, x, Wih0f, b0f, WxF, TT, NG, 300, 300);
    gemm_f32_k<<<dim3(16, 32), 256, 0, stream>>>(emb, nullptr, x, Wih0b, b0b, WxB, TT, NG, 300, 300);
    lstm_phase_k<<<64, 512, 0, stream>>>(WxF, WxB, Whh0f, Whh0b, histF, histB, 0);
    // layer 1 input projections (A = concat(histF, histB), plain layer-0 bits)
    gemm_f32_k<<<dim3(16, 32), 256, 0, stream>>>(histF, histB, nullptr, Wih1f, b1f, WxF, TT, NG, 1024, 512);
    gemm_f32_k<<<dim3(16, 32), 256, 0, stream>>>(histF, histB, nullptr, Wih1b, b1b, WxB, TT, NG, 1024, 512);
    lstm_phase_k<<<64, 512, 0, stream>>>(WxF, WxB, Whh1f, Whh1b, histF, histB, 1);
    classifier_k<<<TT, 64, 0, stream>>>(histF, histB, Wc, bc, out_sc);
    viterbi_k<<<1, 64, 0, stream>>>(out_sc, trans, startv, endv, bp, out_tags);
}

// Round 3
// 17662.546 us; speedup vs baseline: 2.0649x; 1.4847x over previous
//
#include <hip/hip_runtime.h>

// BiLSTM-CRF tagger. V=100000 E=300 H=512 C=40 T=4096. ALL I/O float32.
// r9 = exact r6 lstm structure (proven stable 7127us/phase) + ONE change:
//   h-store is now an explicit SYSTEM-scope write-through (sc0 sc1) instead of
//   agent-scope. Theory: agent store's guaranteed point is the XCD L2; MALL
//   visibility rode on lazy L2 writeback, adding variable latency to every
//   step's store->poll chain. sc0 sc1 write-through removes it. Store remains
//   ONE coalesced 16-lane wave instruction (r8 post-mortem: fragmenting it
//   into 8 per-wave stores quadrupled WRITE_SIZE and gated chunk validity on
//   the slowest of 4 producer waves -> 11.4-43ms bimodal. Never again.)
// Sync scheme (r4/r5/r6, proven): h words self-validate —
//   phase 0 stored plain (valid iff != 0xAAAAAAAA ws poison);
//   phase 1 stored with exponent flipped (^0x7F800000): |h|<1 => enc exp>=128,
//   distinguishable from poison (exp 85) and stale layer-0 values (exp<=127).

typedef unsigned int u32;
typedef unsigned long long u64;
typedef u32 u32x4 __attribute__((ext_vector_type(4)));

#define TT 4096
#define HH 512
#define CC 40
#define NG 2048  // 4*H gate rows

__device__ __forceinline__ float sigm(float x) { return 1.0f / (1.0f + __expf(-x)); }
__device__ __forceinline__ float tanh_(float x) { return 1.0f - 2.0f / (__expf(2.0f * x) + 1.0f); }

// system-scope write-through store: lands at MALL (the pollers' read point)
// without waiting for L2 writeback. Fire-and-forget.
__device__ __forceinline__ void st_sys_u32(u32* p, u32 v) {
    asm volatile("global_store_dword %0, %1, off sc0 sc1"
                 :
                 : "v"(p), "v"(v)
                 : "memory");
}

// 32B system-scope-fresh load (bypass L1+L2, read at MALL). Non-atomic: plain
// read path, no atomic-pipe serialization. waitcnt inside: compiler doesn't
// track asm load results.
__device__ __forceinline__ void ld_mall_b256(const float* p, u32x4& r0, u32x4& r1) {
    asm volatile(
        "global_load_dwordx4 %0, %2, off sc0 sc1\n\t"
        "global_load_dwordx4 %1, %2, off offset:16 sc0 sc1\n\t"
        "s_waitcnt vmcnt(0)"
        : "=&v"(r0), "=&v"(r1)
        : "v"(p)
        : "memory");
}

// ---------------- f32 GEMM: C[M,N] = A @ W^T + bias ----------------
// A row m: xidx ? emb[xidx[m]] (K cols) : concat(A0[m](Ksplit), A1[m](K-Ksplit)).
// 128x128 tile, 256 threads, 8x8 micro split as (4+4)x(4+4) halves 64 apart
// (keeps all LDS reads broadcast or 2-way). BK=8 panels, reg-prefetched staging.
__global__ __launch_bounds__(256, 2) void gemm_f32_k(const float* __restrict__ A0,
                                                     const float* __restrict__ A1,
                                                     const int* __restrict__ xidx,
                                                     const float* __restrict__ W,
                                                     const float* __restrict__ bias,
                                                     float* __restrict__ C,
                                                     int M, int N, int K, int Ksplit) {
    __shared__ float sA[8][132];
    __shared__ float sW[8][132];
    int tid = threadIdx.x;
    int bn = blockIdx.x, bm = blockIdx.y;
    int tx = tid & 15, ty = tid >> 4;
    int srow = tid >> 1, skh = (tid & 1) * 4;  // staging: row 0..127, k-half 0/4

    int am = bm * 128 + srow;
    const float* arow0;
    const float* arow1 = nullptr;
    if (xidx) {
        arow0 = A0 + (size_t)xidx[am] * K;
    } else {
        arow0 = A0 + (size_t)am * Ksplit;
        arow1 = A1 + (size_t)am * Ksplit;
    }
    const float* wrow = W + (size_t)(bn * 128 + srow) * K;

    float acc[2][2][4][4] = {};  // [mhalf][nhalf][mi][ni]

    for (int kc = 0; kc < K; kc += 8) {
        float4 av, wv;
        int k0 = kc + skh;
        if (kc + 8 <= K) {
            if (xidx || k0 + 4 <= Ksplit) av = *(const float4*)(arow0 + k0);
            else                          av = *(const float4*)(arow1 + (k0 - Ksplit));
            wv = *(const float4*)(wrow + k0);
        } else {  // K tail (K=300): per-element mask
            float a_[4], w_[4];
#pragma unroll
            for (int j = 0; j < 4; j++) {
                int k = k0 + j;
                bool ok = k < K;
                a_[j] = ok ? ((xidx || k < Ksplit) ? arow0[k] : arow1[k - Ksplit]) : 0.f;
                w_[j] = ok ? wrow[k] : 0.f;
            }
            av = make_float4(a_[0], a_[1], a_[2], a_[3]);
            wv = make_float4(w_[0], w_[1], w_[2], w_[3]);
        }
        __syncthreads();
        sA[skh + 0][srow] = av.x; sA[skh + 1][srow] = av.y;
        sA[skh + 2][srow] = av.z; sA[skh + 3][srow] = av.w;
        sW[skh + 0][srow] = wv.x; sW[skh + 1][srow] = wv.y;
        sW[skh + 2][srow] = wv.z; sW[skh + 3][srow] = wv.w;
        __syncthreads();
#pragma unroll
        for (int k = 0; k < 8; k++) {
            float4 a0 = *(const float4*)&sA[k][ty * 4];
            float4 a1 = *(const float4*)&sA[k][64 + ty * 4];
            float4 w0 = *(const float4*)&sW[k][tx * 4];
            float4 w1 = *(const float4*)&sW[k][64 + tx * 4];
            float am_[2][4] = {{a0.x, a0.y, a0.z, a0.w}, {a1.x, a1.y, a1.z, a1.w}};
            float wn_[2][4] = {{w0.x, w0.y, w0.z, w0.w}, {w1.x, w1.y, w1.z, w1.w}};
#pragma unroll
            for (int p = 0; p < 2; p++)
#pragma unroll
                for (int q = 0; q < 2; q++)
#pragma unroll
                    for (int mi = 0; mi < 4; mi++)
#pragma unroll
                        for (int ni = 0; ni < 4; ni++)
                            acc[p][q][mi][ni] += am_[p][mi] * wn_[q][ni];
        }
    }

#pragma unroll
    for (int q = 0; q < 2; q++) {
        int gn = bn * 128 + q * 64 + tx * 4;
        float4 b4 = *(const float4*)&bias[gn];
#pragma unroll
        for (int p = 0; p < 2; p++) {
            int gm = bm * 128 + p * 64 + ty * 4;
#pragma unroll
            for (int mi = 0; mi < 4; mi++) {
                float4 o;
                o.x = acc[p][q][mi][0] + b4.x; o.y = acc[p][q][mi][1] + b4.y;
                o.z = acc[p][q][mi][2] + b4.z; o.w = acc[p][q][mi][3] + b4.w;
                *(float4*)&C[(size_t)(gm + mi) * N + gn] = o;
            }
        }
    }
}

// ---------------- LSTM recurrent phase (r6 structure, r9 store scope) ----------------
// 64 blocks x 512 threads: dir = blk>>5, wg = blk&31 owns h[wg*16..+16).
// Thread (r=tid>>3, seg=tid&7): gate row grow=(r>>4)*512 + wg*16 + (r&15),
// k in [seg*64,+64). 64 Whh weights/thread in arch VGPRs. Pollers tid<62 spin on
// remote 32B h chunks (non-atomic sc0 sc1 dwordx4 pairs) until all 8 words pass
// the phase validity predicate, decode, drop into LDS. tid<16 computes gates,
// stores h (SYSTEM scope write-through, one coalesced wave-instr) and writes
// own LDS slice.
__global__ __attribute__((amdgpu_flat_work_group_size(512, 512), amdgpu_waves_per_eu(2, 2)))
void lstm_phase_k(const float* __restrict__ WxF,
                  const float* __restrict__ WxB,
                  const float* __restrict__ WhhF,
                  const float* __restrict__ WhhB,
                  float* __restrict__ histF,
                  float* __restrict__ histB,
                  int phase) {
    const int wg = blockIdx.x & 31;
    const int dir = blockIdx.x >> 5;
    const int tid = threadIdx.x;
    const float* Wx = dir ? WxB : WxF;
    const float* Whh = dir ? WhhB : WhhF;
    float* hist = dir ? histB : histF;
    const u32 ENC = phase ? 0x7F800000u : 0u;

    const int r = tid >> 3, seg = tid & 7;
    const int grow = (r >> 4) * 512 + wg * 16 + (r & 15);

    float w[64];
    {
        const float* wr = Whh + (size_t)grow * HH + seg * 64;
#pragma unroll
        for (int i = 0; i < 16; i++) {
            float4 v = *(const float4*)(wr + i * 4);
            w[i * 4 + 0] = v.x; w[i * 4 + 1] = v.y; w[i * 4 + 2] = v.z; w[i * 4 + 3] = v.w;
        }
    }

    // 32B-chunk index this thread polls (64 chunks of 8 floats; skip own wg's 2)
    const int j = (tid < 62) ? (tid + (tid >= wg * 2 ? 2 : 0)) : 0;

    __shared__ float lds_h[8 * 68];  // 8 seg-chunks of 64, stride 68
    __shared__ float lds_g[64];
    float c_state = 0.f;
    int capped = 0;

    for (int s = 0; s < TT; ++s) {
        const int t = dir ? (TT - 1 - s) : s;
        float wxv = 0.f;
        if (seg == 0) wxv = Wx[(size_t)t * NG + grow];  // prefetch, hidden behind poll

        if (s > 0) {
            const int tprev = dir ? (t + 1) : (t - 1);
            if (tid < 62) {
                const float* p = hist + (size_t)tprev * HH + j * 8;
                u32x4 v0, v1;
                if (!capped) {
                    int it = 0;
                    for (;;) {
                        ld_mall_b256(p, v0, v1);
                        bool ok;
                        if (phase) {
                            ok = ((v0.x & 0x7F800000u) >= 0x40000000u) &&
                                 ((v0.y & 0x7F800000u) >= 0x40000000u) &&
                                 ((v0.z & 0x7F800000u) >= 0x40000000u) &&
                                 ((v0.w & 0x7F800000u) >= 0x40000000u) &&
                                 ((v1.x & 0x7F800000u) >= 0x40000000u) &&
                                 ((v1.y & 0x7F800000u) >= 0x40000000u) &&
                                 ((v1.z & 0x7F800000u) >= 0x40000000u) &&
                                 ((v1.w & 0x7F800000u) >= 0x40000000u);
                        } else {
                            ok = (v0.x != 0xAAAAAAAAu) && (v0.y != 0xAAAAAAAAu) &&
                                 (v0.z != 0xAAAAAAAAu) && (v0.w != 0xAAAAAAAAu) &&
                                 (v1.x != 0xAAAAAAAAu) && (v1.y != 0xAAAAAAAAu) &&
                                 (v1.z != 0xAAAAAAAAu) && (v1.w != 0xAAAAAAAAu);
                        }
                        if (ok) break;
                        if (++it > (1 << 18)) { capped = 1; break; }  // sticky: never hang
                    }
                } else {
                    ld_mall_b256(p, v0, v1);
                }
                float* dst = &lds_h[(j >> 3) * 68 + ((j & 7) * 8)];
                float4 f0, f1;
                f0.x = __uint_as_float(v0.x ^ ENC); f0.y = __uint_as_float(v0.y ^ ENC);
                f0.z = __uint_as_float(v0.z ^ ENC); f0.w = __uint_as_float(v0.w ^ ENC);
                f1.x = __uint_as_float(v1.x ^ ENC); f1.y = __uint_as_float(v1.y ^ ENC);
                f1.z = __uint_as_float(v1.z ^ ENC); f1.w = __uint_as_float(v1.w ^ ENC);
                *(float4*)dst = f0;
                *(float4*)(dst + 4) = f1;
            }
            __syncthreads();
            float a0 = 0.f, a1 = 0.f, a2 = 0.f, a3 = 0.f;
            const float4* hv4 = (const float4*)&lds_h[seg * 68];
#pragma unroll
            for (int i = 0; i < 16; i++) {
                float4 hv = hv4[i];
                a0 += w[i * 4 + 0] * hv.x;
                a1 += w[i * 4 + 1] * hv.y;
                a2 += w[i * 4 + 2] * hv.z;
                a3 += w[i * 4 + 3] * hv.w;
            }
            float acc = (a0 + a1) + (a2 + a3);
            acc += __shfl_xor(acc, 1);
            acc += __shfl_xor(acc, 2);
            acc += __shfl_xor(acc, 4);
            if (seg == 0) lds_g[r] = acc + wxv;
        } else {
            if (seg == 0) lds_g[r] = wxv;
        }
        __syncthreads();

        if (tid < 16) {
            float gi = lds_g[tid], gf = lds_g[16 + tid], gg = lds_g[32 + tid], go = lds_g[48 + tid];
            float iv = sigm(gi), fv = sigm(gf), gv = tanh_(gg), ov = sigm(go);
            c_state = fv * c_state + iv * gv;
            float h = ov * tanh_(c_state);
            int hidx = wg * 16 + tid;
            lds_h[(hidx >> 6) * 68 + (hidx & 63)] = h;  // own slice for next step's dot
            st_sys_u32((u32*)&hist[(size_t)t * HH + hidx], __float_as_uint(h) ^ ENC);
        }
        // no end barrier: remote LDS slices are dead until the next poll barrier,
        // and lds_g is rewritten only after that barrier (which waits for tid<16).
    }
}

// ---------------- classifier + log_softmax (writes scores to d_out) ----------------
// hist holds phase-1 encoding: decode = xor 0x7F800000 per word.
__global__ __launch_bounds__(64, 4) void classifier_k(const float* __restrict__ histF,
                                                      const float* __restrict__ histB,
                                                      const float* __restrict__ Wc,
                                                      const float* __restrict__ bc,
                                                      float* __restrict__ outsc) {
    int t = blockIdx.x, lane = threadIdx.x;
    __shared__ float hrow[1024];
    const uint4* hf4 = (const uint4*)(histF + (size_t)t * HH);
    const uint4* hb4 = (const uint4*)(histB + (size_t)t * HH);
#pragma unroll
    for (int jj = 0; jj < 4; jj++) {
        int idx4 = jj * 64 + lane;  // 0..255 uint4s
        uint4 u = (idx4 < 128) ? hf4[idx4] : hb4[idx4 - 128];
        u.x ^= 0x7F800000u; u.y ^= 0x7F800000u; u.z ^= 0x7F800000u; u.w ^= 0x7F800000u;
        float4 v;
        v.x = __uint_as_float(u.x); v.y = __uint_as_float(u.y);
        v.z = __uint_as_float(u.z); v.w = __uint_as_float(u.w);
        *(float4*)&hrow[idx4 * 4] = v;
    }
    __syncthreads();
    float o = 0.f;
    if (lane < CC) {
        o = bc[lane];
        const float4* wr = (const float4*)(Wc + (size_t)lane * 1024);
#pragma unroll 4
        for (int kk = 0; kk < 256; ++kk) {
            float4 w4 = wr[kk];
            float4 h4 = *(const float4*)&hrow[kk * 4];
            o += w4.x * h4.x + w4.y * h4.y + w4.z * h4.z + w4.w * h4.w;
        }
    }
    float m = (lane < CC) ? o : -1e30f;
#pragma unroll
    for (int d = 1; d < 64; d <<= 1) m = fmaxf(m, __shfl_xor(m, d));
    float ex = (lane < CC) ? __expf(o - m) : 0.f;
#pragma unroll
    for (int d = 1; d < 64; d <<= 1) ex += __shfl_xor(ex, d);
    float lse = m + __logf(ex);
    if (lane < CC) outsc[(size_t)t * CC + lane] = o - lse;
}

// ---------------- viterbi forward + backtrack (single wave, shfl broadcast) ----------------
__global__ __launch_bounds__(64) void viterbi_k(const float* __restrict__ em,
                                               const float* __restrict__ trans,
                                               const float* __restrict__ startv,
                                               const float* __restrict__ endv,
                                               unsigned char* __restrict__ bp,
                                               float* __restrict__ outtags) {
    int lane = threadIdx.x;
    float tcol[CC];
#pragma unroll
    for (int p = 0; p < CC; p++) tcol[p] = 0.f;
    if (lane < CC) {
#pragma unroll
        for (int p = 0; p < CC; p++) tcol[p] = trans[p * CC + lane];  // trans[prev][next=lane]
    }
    float s = (lane < CC) ? (startv[lane] + em[lane]) : 0.f;

    for (int t = 1; t < TT; ++t) {
        float emv = (lane < CC) ? em[(size_t)t * CC + lane] : 0.f;
        float b0 = -1e30f, b1 = -1e30f;
        int i0 = 0, i1 = 20;
#pragma unroll
        for (int p = 0; p < 20; p++) {
            float c0 = __shfl(s, p) + tcol[p];
            float c1 = __shfl(s, p + 20) + tcol[p + 20];
            if (c0 > b0) { b0 = c0; i0 = p; }       // strict > = first-max
            if (c1 > b1) { b1 = c1; i1 = p + 20; }
        }
        float best = b0; int bi = i0;
        if (b1 > b0) { best = b1; bi = i1; }        // tie -> lower-index chain 0
        s = best + emv;
        if (lane < CC) bp[(size_t)t * CC + lane] = (unsigned char)bi;
    }
    float fv = (lane < CC) ? (s + endv[lane]) : -1e30f;
    int fi = (lane < CC) ? lane : 63;
#pragma unroll
    for (int d = 1; d < 64; d <<= 1) {
        float ov = __shfl_xor(fv, d);
        int oi = __shfl_xor(fi, d);
        if (ov > fv || (ov == fv && oi < fi)) { fv = ov; fi = oi; }
    }
    __threadfence();   // bp stores (lanes 0..39) visible to lane 0's loads
    if (lane == 0) {
        int cur = fi;
        outtags[TT - 1] = (float)cur;
        for (int t = TT - 2; t >= 0; --t) {
            cur = bp[(size_t)(t + 1) * CC + cur];
            outtags[t] = (float)cur;
        }
    }
}

extern "C" void kernel_launch(void* const* d_in, const int* in_sizes, int n_in,
                              void* d_out, int out_size, void* d_ws, size_t ws_size,
                              hipStream_t stream) {
    const int*   x     = (const int*)d_in[0];
    const float* emb   = (const float*)d_in[1];
    const float* Wih0f = (const float*)d_in[2];
    const float* Whh0f = (const float*)d_in[3];
    const float* b0f   = (const float*)d_in[4];
    const float* Wih0b = (const float*)d_in[5];
    const float* Whh0b = (const float*)d_in[6];
    const float* b0b   = (const float*)d_in[7];
    const float* Wih1f = (const float*)d_in[8];
    const float* Whh1f = (const float*)d_in[9];
    const float* b1f   = (const float*)d_in[10];
    const float* Wih1b = (const float*)d_in[11];
    const float* Whh1b = (const float*)d_in[12];
    const float* b1b   = (const float*)d_in[13];
    const float* Wc    = (const float*)d_in[14];
    const float* bc    = (const float*)d_in[15];
    const float* trans = (const float*)d_in[16];
    const float* startv= (const float*)d_in[17];
    const float* endv  = (const float*)d_in[18];

    char* ws = (char*)d_ws;
    // layout, total 84,148,224 B
    unsigned char* bp = (unsigned char*)(ws + 1024);       // 4096*40 = 163,840
    float* WxF  = (float*)(ws + 262144);                   // 4096*2048*4 = 33,554,432
    float* WxB  = (float*)(ws + 33816576);                 // 33,554,432
    float* histF= (float*)(ws + 67371008);                 // 4096*512*4 = 8,388,608
    float* histB= (float*)(ws + 75759616);                 // 8,388,608 -> 84,148,224

    if (ws_size < (size_t)84148224) return;  // diagnostic: zero output => ws too small

    float* out_sc   = (float*)d_out;                 // 4096*40 scores
    float* out_tags = out_sc + (size_t)TT * CC;      // 4096 tags (as float)

    // layer 0 input projections (emb gather fused into GEMM)
    gemm_f32_k<<<dim3(16, 32), 256, 0, stream>>>(emb, nullptr, x, Wih0f, b0f, WxF, TT, NG, 300, 300);
    gemm_f32_k<<<dim3(16, 32), 256, 0, stream>>>(emb, nullptr, x, Wih0b, b0b, WxB, TT, NG, 300, 300);
    lstm_phase_k<<<64, 512, 0, stream>>>(WxF, WxB, Whh0f, Whh0b, histF, histB, 0);
    // layer 1 input projections (A = concat(histF, histB), plain layer-0 bits)
    gemm_f32_k<<<dim3(16, 32), 256, 0, stream>>>(histF, histB, nullptr, Wih1f, b1f, WxF, TT, NG, 1024, 512);
    gemm_f32_k<<<dim3(16, 32), 256, 0, stream>>>(histF, histB, nullptr, Wih1b, b1b, WxB, TT, NG, 1024, 512);
    lstm_phase_k<<<64, 512, 0, stream>>>(WxF, WxB, Whh1f, Whh1b, histF, histB, 1);
    classifier_k<<<TT, 64, 0, stream>>>(histF, histB, Wc, bc, out_sc);
    viterbi_k<<<1, 64, 0, stream>>>(out_sc, trans, startv, endv, bp, out_tags);
}

// Round 6
// 17287.875 us; speedup vs baseline: 2.1097x; 1.0217x over previous
//
#include <hip/hip_runtime.h>

// BiLSTM-CRF tagger. V=100000 E=300 H=512 C=40 T=4096. ALL I/O float32.
// r12 = r9 lstm/classifier/viterbi (proven 17.66ms pass) + split-bf16 MFMA GEMM.
//   GEMM: C = A @ W^T + bias via 3-term bf16 split (x = hi + lo, products
//   Ah*Bh + Ah*Bl + Al*Bh; error ~2^-16 rel, far below the 0.0156 bf16 readout
//   granularity the f32 version already passed at). mfma_f32_16x16x32_bf16,
//   layouts per m89/m91 (A/B: free=lane&15, k=(lane>>4)*8+j; D: col=lane&15,
//   row=(lane>>4)*4+reg). f32->2xbf16 conversion paid once per LDS tile.
// r11 lesson: counted-vmcnt poll split across asm blocks is unsafe (compiler
//   may v_mov-copy in-flight load dest regs before the wait); only a single
//   mega-asm block could do it. Not retried here.
// r10 lesson: append-only polled addresses + sc0sc1 (MALL) ops are the only
//   proven-safe sync combination.
// Sync scheme (r4..r9, proven): h words self-validate — phase 0 plain
//   (valid iff != 0xAAAAAAAA ws poison); phase 1 exp-flipped (^0x7F800000).

typedef unsigned int u32;
typedef unsigned long long u64;
typedef u32 u32x4 __attribute__((ext_vector_type(4)));
typedef __attribute__((ext_vector_type(8))) short s16x8;   // 8 bf16 (4 VGPRs)
typedef __attribute__((ext_vector_type(4))) float f32x4;

#define TT 4096
#define HH 512
#define CC 40
#define NG 2048  // 4*H gate rows

__device__ __forceinline__ float sigm(float x) { return 1.0f / (1.0f + __expf(-x)); }
__device__ __forceinline__ float tanh_(float x) { return 1.0f - 2.0f / (__expf(2.0f * x) + 1.0f); }

// system-scope write-through store: lands at MALL (the pollers' read point).
__device__ __forceinline__ void st_sys_u32(u32* p, u32 v) {
    asm volatile("global_store_dword %0, %1, off sc0 sc1"
                 :
                 : "v"(p), "v"(v)
                 : "memory");
}

// 32B system-scope-fresh load (bypass L1+L2, read at MALL).
__device__ __forceinline__ void ld_mall_b256(const float* p, u32x4& r0, u32x4& r1) {
    asm volatile(
        "global_load_dwordx4 %0, %2, off sc0 sc1\n\t"
        "global_load_dwordx4 %1, %2, off offset:16 sc0 sc1\n\t"
        "s_waitcnt vmcnt(0)"
        : "=&v"(r0), "=&v"(r1)
        : "v"(p)
        : "memory");
}

// ---------------- split-bf16 MFMA GEMM: C[M,N] = A @ W^T + bias ----------------
// A row m: xidx ? emb[xidx[m]] (K cols) : concat(A0[m](Ksplit), A1[m](K-Ksplit)).
// 128x128 tile, 256 threads = 4 waves, each wave a 64x64 quadrant of 4x4
// 16x16 MFMA tiles. BK=32 panels. f32 staged into LDS as hi/lo bf16 planes
// (conversion amortized over the tile). XOR chunk swizzle: 16B chunk c at row
// stored at c ^ ((row>>1)&3) -> frag ds_read_b128 is 2-way (free).
__device__ __forceinline__ void split_pack8(const float* f, s16x8& hi, s16x8& lo) {
#pragma unroll
    for (int j = 0; j < 8; j++) {
        float x = f[j];
        u32 h = __float_as_uint(x) & 0xFFFF0000u;
        float hf = __uint_as_float(h);
        hi[j] = (short)(h >> 16);
        lo[j] = (short)(__float_as_uint(x - hf) >> 16);
    }
}

__global__ __launch_bounds__(256, 2) void gemm_bf16s_k(const float* __restrict__ A0,
                                                       const float* __restrict__ A1,
                                                       const int* __restrict__ xidx,
                                                       const float* __restrict__ W,
                                                       const float* __restrict__ bias,
                                                       float* __restrict__ C,
                                                       int M, int N, int K, int Ksplit) {
    __shared__ __align__(16) short sAh[128 * 32];
    __shared__ __align__(16) short sAl[128 * 32];
    __shared__ __align__(16) short sWh[128 * 32];
    __shared__ __align__(16) short sWl[128 * 32];
    const int tid = threadIdx.x;
    const int bn = blockIdx.x, bm = blockIdx.y;
    const int wid = tid >> 6, lane = tid & 63;
    const int qm = (wid >> 1) * 64, qn = (wid & 1) * 64;  // wave quadrant
    const int fr = lane & 15, fq = lane >> 4;             // frag free idx, k-group

    // staging: thread -> row 0..127, k-half 0/16
    const int srow = tid >> 1;
    const int kh = (tid & 1) * 16;

    const int am = bm * 128 + srow;
    const float* arow = xidx ? (A0 + (size_t)xidx[am] * K) : nullptr;
    const float* a0r = xidx ? nullptr : (A0 + (size_t)am * Ksplit);
    const float* a1r = xidx ? nullptr : (A1 + (size_t)am * Ksplit);
    const float* wrow = W + (size_t)(bn * 128 + srow) * K;

    f32x4 acc[4][4] = {};

    const int NP = (K + 31) >> 5;
    for (int kp = 0; kp < NP; kp++) {
        const int kb = kp * 32 + kh;
        float fa[16], fw[16];
        if (kb + 16 <= K) {
#pragma unroll
            for (int j = 0; j < 16; j += 4) {
                int k = kb + j;
                const float* s = xidx ? (arow + k)
                                      : ((k < Ksplit) ? (a0r + k) : (a1r + (k - Ksplit)));
                float4 v = *(const float4*)s;
                fa[j] = v.x; fa[j + 1] = v.y; fa[j + 2] = v.z; fa[j + 3] = v.w;
                float4 wv = *(const float4*)(wrow + k);
                fw[j] = wv.x; fw[j + 1] = wv.y; fw[j + 2] = wv.z; fw[j + 3] = wv.w;
            }
        } else {  // K tail (K=300): per-element mask, zero-pad
#pragma unroll
            for (int j = 0; j < 16; j++) {
                int k = kb + j;
                float av = 0.f, wv = 0.f;
                if (k < K) {
                    av = xidx ? arow[k] : ((k < Ksplit) ? a0r[k] : a1r[k - Ksplit]);
                    wv = wrow[k];
                }
                fa[j] = av; fw[j] = wv;
            }
        }
        __syncthreads();  // previous panel's frag reads complete
#pragma unroll
        for (int c = 0; c < 2; c++) {
            int ch = (tid & 1) * 2 + c;
            int pch = ch ^ ((srow >> 1) & 3);
            int off = srow * 32 + pch * 8;
            s16x8 hi, lo;
            split_pack8(fa + c * 8, hi, lo);
            *(s16x8*)&sAh[off] = hi;
            *(s16x8*)&sAl[off] = lo;
            split_pack8(fw + c * 8, hi, lo);
            *(s16x8*)&sWh[off] = hi;
            *(s16x8*)&sWl[off] = lo;
        }
        __syncthreads();

        s16x8 ah[4], al[4];
#pragma unroll
        for (int m = 0; m < 4; m++) {
            int row = qm + m * 16 + fr;
            int off = row * 32 + ((fq ^ ((row >> 1) & 3)) * 8);
            ah[m] = *(const s16x8*)&sAh[off];
            al[m] = *(const s16x8*)&sAl[off];
        }
#pragma unroll
        for (int n = 0; n < 4; n++) {
            int row = qn + n * 16 + fr;
            int off = row * 32 + ((fq ^ ((row >> 1) & 3)) * 8);
            s16x8 bh = *(const s16x8*)&sWh[off];
            s16x8 bl = *(const s16x8*)&sWl[off];
#pragma unroll
            for (int m = 0; m < 4; m++) {
                acc[m][n] = __builtin_amdgcn_mfma_f32_16x16x32_bf16(ah[m], bh, acc[m][n], 0, 0, 0);
                acc[m][n] = __builtin_amdgcn_mfma_f32_16x16x32_bf16(ah[m], bl, acc[m][n], 0, 0, 0);
                acc[m][n] = __builtin_amdgcn_mfma_f32_16x16x32_bf16(al[m], bh, acc[m][n], 0, 0, 0);
            }
        }
    }

#pragma unroll
    for (int n = 0; n < 4; n++) {
        int gcol = bn * 128 + qn + n * 16 + fr;
        float b = bias[gcol];
#pragma unroll
        for (int m = 0; m < 4; m++) {
            int rbase = bm * 128 + qm + m * 16 + fq * 4;
#pragma unroll
            for (int r2 = 0; r2 < 4; r2++)
                C[(size_t)(rbase + r2) * N + gcol] = acc[m][n][r2] + b;
        }
    }
}

// ---------------- LSTM recurrent phase (r9, byte-for-byte) ----------------
// 64 blocks x 512 threads: dir = blk>>5, wg = blk&31 owns h[wg*16..+16).
// Thread (r=tid>>3, seg=tid&7): gate row grow=(r>>4)*512 + wg*16 + (r&15),
// k in [seg*64,+64). 64 Whh weights/thread in arch VGPRs. Pollers tid<62 spin on
// remote 32B h chunks (non-atomic sc0 sc1 dwordx4 pairs) until all 8 words pass
// the phase validity predicate, decode, drop into LDS. tid<16 computes gates,
// stores h (SYSTEM scope write-through, one coalesced wave-instr) and writes
// own LDS slice.
__global__ __attribute__((amdgpu_flat_work_group_size(512, 512), amdgpu_waves_per_eu(2, 2)))
void lstm_phase_k(const float* __restrict__ WxF,
                  const float* __restrict__ WxB,
                  const float* __restrict__ WhhF,
                  const float* __restrict__ WhhB,
                  float* __restrict__ histF,
                  float* __restrict__ histB,
                  int phase) {
    const int wg = blockIdx.x & 31;
    const int dir = blockIdx.x >> 5;
    const int tid = threadIdx.x;
    const float* Wx = dir ? WxB : WxF;
    const float* Whh = dir ? WhhB : WhhF;
    float* hist = dir ? histB : histF;
    const u32 ENC = phase ? 0x7F800000u : 0u;

    const int r = tid >> 3, seg = tid & 7;
    const int grow = (r >> 4) * 512 + wg * 16 + (r & 15);

    float w[64];
    {
        const float* wr = Whh + (size_t)grow * HH + seg * 64;
#pragma unroll
        for (int i = 0; i < 16; i++) {
            float4 v = *(const float4*)(wr + i * 4);
            w[i * 4 + 0] = v.x; w[i * 4 + 1] = v.y; w[i * 4 + 2] = v.z; w[i * 4 + 3] = v.w;
        }
    }

    // 32B-chunk index this thread polls (64 chunks of 8 floats; skip own wg's 2)
    const int j = (tid < 62) ? (tid + (tid >= wg * 2 ? 2 : 0)) : 0;

    __shared__ float lds_h[8 * 68];  // 8 seg-chunks of 64, stride 68
    __shared__ float lds_g[64];
    float c_state = 0.f;
    int capped = 0;

    for (int s = 0; s < TT; ++s) {
        const int t = dir ? (TT - 1 - s) : s;
        float wxv = 0.f;
        if (seg == 0) wxv = Wx[(size_t)t * NG + grow];  // prefetch, hidden behind poll

        if (s > 0) {
            const int tprev = dir ? (t + 1) : (t - 1);
            if (tid < 62) {
                const float* p = hist + (size_t)tprev * HH + j * 8;
                u32x4 v0, v1;
                if (!capped) {
                    int it = 0;
                    for (;;) {
                        ld_mall_b256(p, v0, v1);
                        bool ok;
                        if (phase) {
                            ok = ((v0.x & 0x7F800000u) >= 0x40000000u) &&
                                 ((v0.y & 0x7F800000u) >= 0x40000000u) &&
                                 ((v0.z & 0x7F800000u) >= 0x40000000u) &&
                                 ((v0.w & 0x7F800000u) >= 0x40000000u) &&
                                 ((v1.x & 0x7F800000u) >= 0x40000000u) &&
                                 ((v1.y & 0x7F800000u) >= 0x40000000u) &&
                                 ((v1.z & 0x7F800000u) >= 0x40000000u) &&
                                 ((v1.w & 0x7F800000u) >= 0x40000000u);
                        } else {
                            ok = (v0.x != 0xAAAAAAAAu) && (v0.y != 0xAAAAAAAAu) &&
                                 (v0.z != 0xAAAAAAAAu) && (v0.w != 0xAAAAAAAAu) &&
                                 (v1.x != 0xAAAAAAAAu) && (v1.y != 0xAAAAAAAAu) &&
                                 (v1.z != 0xAAAAAAAAu) && (v1.w != 0xAAAAAAAAu);
                        }
                        if (ok) break;
                        if (++it > (1 << 18)) { capped = 1; break; }  // sticky: never hang
                    }
                } else {
                    ld_mall_b256(p, v0, v1);
                }
                float* dst = &lds_h[(j >> 3) * 68 + ((j & 7) * 8)];
                float4 f0, f1;
                f0.x = __uint_as_float(v0.x ^ ENC); f0.y = __uint_as_float(v0.y ^ ENC);
                f0.z = __uint_as_float(v0.z ^ ENC); f0.w = __uint_as_float(v0.w ^ ENC);
                f1.x = __uint_as_float(v1.x ^ ENC); f1.y = __uint_as_float(v1.y ^ ENC);
                f1.z = __uint_as_float(v1.z ^ ENC); f1.w = __uint_as_float(v1.w ^ ENC);
                *(float4*)dst = f0;
                *(float4*)(dst + 4) = f1;
            }
            __syncthreads();
            float a0 = 0.f, a1 = 0.f, a2 = 0.f, a3 = 0.f;
            const float4* hv4 = (const float4*)&lds_h[seg * 68];
#pragma unroll
            for (int i = 0; i < 16; i++) {
                float4 hv = hv4[i];
                a0 += w[i * 4 + 0] * hv.x;
                a1 += w[i * 4 + 1] * hv.y;
                a2 += w[i * 4 + 2] * hv.z;
                a3 += w[i * 4 + 3] * hv.w;
            }
            float acc = (a0 + a1) + (a2 + a3);
            acc += __shfl_xor(acc, 1);
            acc += __shfl_xor(acc, 2);
            acc += __shfl_xor(acc, 4);
            if (seg == 0) lds_g[r] = acc + wxv;
        } else {
            if (seg == 0) lds_g[r] = wxv;
        }
        __syncthreads();

        if (tid < 16) {
            float gi = lds_g[tid], gf = lds_g[16 + tid], gg = lds_g[32 + tid], go = lds_g[48 + tid];
            float iv = sigm(gi), fv = sigm(gf), gv = tanh_(gg), ov = sigm(go);
            c_state = fv * c_state + iv * gv;
            float h = ov * tanh_(c_state);
            int hidx = wg * 16 + tid;
            lds_h[(hidx >> 6) * 68 + (hidx & 63)] = h;  // own slice for next step's dot
            st_sys_u32((u32*)&hist[(size_t)t * HH + hidx], __float_as_uint(h) ^ ENC);
        }
        // no end barrier: remote LDS slices are dead until the next poll barrier,
        // and lds_g is rewritten only after that barrier (which waits for tid<16).
    }
}

// ---------------- classifier + log_softmax (writes scores to d_out) ----------------
// hist holds phase-1 encoding: decode = xor 0x7F800000 per word.
__global__ __launch_bounds__(64, 4) void classifier_k(const float* __restrict__ histF,
                                                      const float* __restrict__ histB,
                                                      const float* __restrict__ Wc,
                                                      const float* __restrict__ bc,
                                                      float* __restrict__ outsc) {
    int t = blockIdx.x, lane = threadIdx.x;
    __shared__ float hrow[1024];
    const uint4* hf4 = (const uint4*)(histF + (size_t)t * HH);
    const uint4* hb4 = (const uint4*)(histB + (size_t)t * HH);
#pragma unroll
    for (int jj = 0; jj < 4; jj++) {
        int idx4 = jj * 64 + lane;  // 0..255 uint4s
        uint4 u = (idx4 < 128) ? hf4[idx4] : hb4[idx4 - 128];
        u.x ^= 0x7F800000u; u.y ^= 0x7F800000u; u.z ^= 0x7F800000u; u.w ^= 0x7F800000u;
        float4 v;
        v.x = __uint_as_float(u.x); v.y = __uint_as_float(u.y);
        v.z = __uint_as_float(u.z); v.w = __uint_as_float(u.w);
        *(float4*)&hrow[idx4 * 4] = v;
    }
    __syncthreads();
    float o = 0.f;
    if (lane < CC) {
        o = bc[lane];
        const float4* wr = (const float4*)(Wc + (size_t)lane * 1024);
#pragma unroll 4
        for (int kk = 0; kk < 256; ++kk) {
            float4 w4 = wr[kk];
            float4 h4 = *(const float4*)&hrow[kk * 4];
            o += w4.x * h4.x + w4.y * h4.y + w4.z * h4.z + w4.w * h4.w;
        }
    }
    float m = (lane < CC) ? o : -1e30f;
#pragma unroll
    for (int d = 1; d < 64; d <<= 1) m = fmaxf(m, __shfl_xor(m, d));
    float ex = (lane < CC) ? __expf(o - m) : 0.f;
#pragma unroll
    for (int d = 1; d < 64; d <<= 1) ex += __shfl_xor(ex, d);
    float lse = m + __logf(ex);
    if (lane < CC) outsc[(size_t)t * CC + lane] = o - lse;
}

// ---------------- viterbi forward + backtrack (single wave, shfl broadcast) ----------------
__global__ __launch_bounds__(64) void viterbi_k(const float* __restrict__ em,
                                               const float* __restrict__ trans,
                                               const float* __restrict__ startv,
                                               const float* __restrict__ endv,
                                               unsigned char* __restrict__ bp,
                                               float* __restrict__ outtags) {
    int lane = threadIdx.x;
    float tcol[CC];
#pragma unroll
    for (int p = 0; p < CC; p++) tcol[p] = 0.f;
    if (lane < CC) {
#pragma unroll
        for (int p = 0; p < CC; p++) tcol[p] = trans[p * CC + lane];  // trans[prev][next=lane]
    }
    float s = (lane < CC) ? (startv[lane] + em[lane]) : 0.f;

    for (int t = 1; t < TT; ++t) {
        float emv = (lane < CC) ? em[(size_t)t * CC + lane] : 0.f;
        float b0 = -1e30f, b1 = -1e30f;
        int i0 = 0, i1 = 20;
#pragma unroll
        for (int p = 0; p < 20; p++) {
            float c0 = __shfl(s, p) + tcol[p];
            float c1 = __shfl(s, p + 20) + tcol[p + 20];
            if (c0 > b0) { b0 = c0; i0 = p; }       // strict > = first-max
            if (c1 > b1) { b1 = c1; i1 = p + 20; }
        }
        float best = b0; int bi = i0;
        if (b1 > b0) { best = b1; bi = i1; }        // tie -> lower-index chain 0
        s = best + emv;
        if (lane < CC) bp[(size_t)t * CC + lane] = (unsigned char)bi;
    }
    float fv = (lane < CC) ? (s + endv[lane]) : -1e30f;
    int fi = (lane < CC) ? lane : 63;
#pragma unroll
    for (int d = 1; d < 64; d <<= 1) {
        float ov = __shfl_xor(fv, d);
        int oi = __shfl_xor(fi, d);
        if (ov > fv || (ov == fv && oi < fi)) { fv = ov; fi = oi; }
    }
    __threadfence();   // bp stores (lanes 0..39) visible to lane 0's loads
    if (lane == 0) {
        int cur = fi;
        outtags[TT - 1] = (float)cur;
        for (int t = TT - 2; t >= 0; --t) {
            cur = bp[(size_t)(t + 1) * CC + cur];
            outtags[t] = (float)cur;
        }
    }
}

extern "C" void kernel_launch(void* const* d_in, const int* in_sizes, int n_in,
                              void* d_out, int out_size, void* d_ws, size_t ws_size,
                              hipStream_t stream) {
    const int*   x     = (const int*)d_in[0];
    const float* emb   = (const float*)d_in[1];
    const float* Wih0f = (const float*)d_in[2];
    const float* Whh0f = (const float*)d_in[3];
    const float* b0f   = (const float*)d_in[4];
    const float* Wih0b = (const float*)d_in[5];
    const float* Whh0b = (const float*)d_in[6];
    const float* b0b   = (const float*)d_in[7];
    const float* Wih1f = (const float*)d_in[8];
    const float* Whh1f = (const float*)d_in[9];
    const float* b1f   = (const float*)d_in[10];
    const float* Wih1b = (const float*)d_in[11];
    const float* Whh1b = (const float*)d_in[12];
    const float* b1b   = (const float*)d_in[13];
    const float* Wc    = (const float*)d_in[14];
    const float* bc    = (const float*)d_in[15];
    const float* trans = (const float*)d_in[16];
    const float* startv= (const float*)d_in[17];
    const float* endv  = (const float*)d_in[18];

    char* ws = (char*)d_ws;
    // layout, total 84,148,224 B
    unsigned char* bp = (unsigned char*)(ws + 1024);       // 4096*40 = 163,840
    float* WxF  = (float*)(ws + 262144);                   // 4096*2048*4 = 33,554,432
    float* WxB  = (float*)(ws + 33816576);                 // 33,554,432
    float* histF= (float*)(ws + 67371008);                 // 4096*512*4 = 8,388,608
    float* histB= (float*)(ws + 75759616);                 // 8,388,608 -> 84,148,224

    if (ws_size < (size_t)84148224) return;  // diagnostic: zero output => ws too small

    float* out_sc   = (float*)d_out;                 // 4096*40 scores
    float* out_tags = out_sc + (size_t)TT * CC;      // 4096 tags (as float)

    // layer 0 input projections (emb gather fused into GEMM)
    gemm_bf16s_k<<<dim3(16, 32), 256, 0, stream>>>(emb, nullptr, x, Wih0f, b0f, WxF, TT, NG, 300, 300);
    gemm_bf16s_k<<<dim3(16, 32), 256, 0, stream>>>(emb, nullptr, x, Wih0b, b0b, WxB, TT, NG, 300, 300);
    lstm_phase_k<<<64, 512, 0, stream>>>(WxF, WxB, Whh0f, Whh0b, histF, histB, 0);
    // layer 1 input projections (A = concat(histF, histB), plain layer-0 bits)
    gemm_bf16s_k<<<dim3(16, 32), 256, 0, stream>>>(histF, histB, nullptr, Wih1f, b1f, WxF, TT, NG, 1024, 512);
    gemm_bf16s_k<<<dim3(16, 32), 256, 0, stream>>>(histF, histB, nullptr, Wih1b, b1b, WxB, TT, NG, 1024, 512);
    lstm_phase_k<<<64, 512, 0, stream>>>(WxF, WxB, Whh1f, Whh1b, histF, histB, 1);
    classifier_k<<<TT, 64, 0, stream>>>(histF, histB, Wc, bc, out_sc);
    viterbi_k<<<1, 64, 0, stream>>>(out_sc, trans, startv, endv, bp, out_tags);
}

// Round 7
// 17252.643 us; speedup vs baseline: 2.1140x; 1.0020x over previous
//
#include <hip/hip_runtime.h>

// BiLSTM-CRF tagger. V=100000 E=300 H=512 C=40 T=4096. ALL I/O float32.
// r13 = r12 (proven 17.29ms pass) + GEMM schedule fix (numerics unchanged):
//   - register prefetch: panel k+1's f32 global loads issued right after the
//     LDS-ready barrier -> latency hidden under the 48-MFMA section (r12
//     exposed the full load latency inside the barrier-bounded region/panel).
//   - split-at-source: f32->bf16 hi/lo conversion on prefetched regs BEFORE
//     the LDS-free barrier (thread-local; overlaps other waves' MFMA).
//   - F/B dispatch merge via grid.z=2 (same A panels, two weight sets) ->
//     4 GEMM dispatches become 2, removing 2 launch gaps.
//   Addressing/swizzle/3-term split math byte-identical to r12 (verified pass).
// r11/r10 lessons: counted-vmcnt poll split across asm blocks is unsafe;
//   append-only polled addresses + sc0sc1 (MALL) ops are the only proven-safe
//   sync combination. lstm/classifier/viterbi: byte-for-byte r12.
// Sync scheme (r4..r9, proven): h words self-validate — phase 0 plain
//   (valid iff != 0xAAAAAAAA ws poison); phase 1 exp-flipped (^0x7F800000).

typedef unsigned int u32;
typedef unsigned long long u64;
typedef u32 u32x4 __attribute__((ext_vector_type(4)));
typedef __attribute__((ext_vector_type(8))) short s16x8;   // 8 bf16 (4 VGPRs)
typedef __attribute__((ext_vector_type(4))) float f32x4;

#define TT 4096
#define HH 512
#define CC 40
#define NG 2048  // 4*H gate rows

__device__ __forceinline__ float sigm(float x) { return 1.0f / (1.0f + __expf(-x)); }
__device__ __forceinline__ float tanh_(float x) { return 1.0f - 2.0f / (__expf(2.0f * x) + 1.0f); }

// system-scope write-through store: lands at MALL (the pollers' read point).
__device__ __forceinline__ void st_sys_u32(u32* p, u32 v) {
    asm volatile("global_store_dword %0, %1, off sc0 sc1"
                 :
                 : "v"(p), "v"(v)
                 : "memory");
}

// 32B system-scope-fresh load (bypass L1+L2, read at MALL).
__device__ __forceinline__ void ld_mall_b256(const float* p, u32x4& r0, u32x4& r1) {
    asm volatile(
        "global_load_dwordx4 %0, %2, off sc0 sc1\n\t"
        "global_load_dwordx4 %1, %2, off offset:16 sc0 sc1\n\t"
        "s_waitcnt vmcnt(0)"
        : "=&v"(r0), "=&v"(r1)
        : "v"(p)
        : "memory");
}

// ---------------- split-bf16 MFMA GEMM (pipelined): C = A @ W^T + bias ----------------
// A row m: xidx ? emb[xidx[m]] (K cols) : concat(A0[m](Ksplit), A1[m](K-Ksplit)).
// grid.z selects (W,bias,C) set: z=0 forward, z=1 backward (same A).
// 128x128 tile, 256 threads = 4 waves, each wave a 64x64 quadrant of 4x4
// 16x16 MFMA tiles. BK=32 panels. XOR chunk swizzle (r12-verified): 16B chunk
// c at row stored at c ^ ((row>>1)&3).
__device__ __forceinline__ void split_pack8(const float* f, s16x8& hi, s16x8& lo) {
#pragma unroll
    for (int j = 0; j < 8; j++) {
        float x = f[j];
        u32 h = __float_as_uint(x) & 0xFFFF0000u;
        float hf = __uint_as_float(h);
        hi[j] = (short)(h >> 16);
        lo[j] = (short)(__float_as_uint(x - hf) >> 16);
    }
}

__global__ __launch_bounds__(256, 2) void gemm_bf16s_k(const float* __restrict__ A0,
                                                       const float* __restrict__ A1,
                                                       const int* __restrict__ xidx,
                                                       const float* __restrict__ W0,
                                                       const float* __restrict__ bias0,
                                                       float* __restrict__ C0,
                                                       const float* __restrict__ W1,
                                                       const float* __restrict__ bias1,
                                                       float* __restrict__ C1,
                                                       int M, int N, int K, int Ksplit) {
    __shared__ __align__(16) short sAh[128 * 32];
    __shared__ __align__(16) short sAl[128 * 32];
    __shared__ __align__(16) short sWh[128 * 32];
    __shared__ __align__(16) short sWl[128 * 32];
    const int tid = threadIdx.x;
    const int bn = blockIdx.x, bm = blockIdx.y;
    const float* W    = blockIdx.z ? W1 : W0;
    const float* bias = blockIdx.z ? bias1 : bias0;
    float*       C    = blockIdx.z ? C1 : C0;
    const int wid = tid >> 6, lane = tid & 63;
    const int qm = (wid >> 1) * 64, qn = (wid & 1) * 64;  // wave quadrant
    const int fr = lane & 15, fq = lane >> 4;             // frag free idx, k-group

    // staging: thread -> row 0..127, k-half 0/16
    const int srow = tid >> 1;
    const int kh = (tid & 1) * 16;

    const int am = bm * 128 + srow;
    const float* arow = xidx ? (A0 + (size_t)xidx[am] * K) : nullptr;
    const float* a0r = xidx ? nullptr : (A0 + (size_t)am * Ksplit);
    const float* a1r = xidx ? nullptr : (A1 + (size_t)am * Ksplit);
    const float* wrow = W + (size_t)(bn * 128 + srow) * K;

    f32x4 acc[4][4] = {};

    // panel load into registers (f32): A/W rows, 16 k-values each.
    auto LOADP = [&](int kp, float* fa, float* fw) {
        const int kb = kp * 32 + kh;
        if (kb + 16 <= K) {
#pragma unroll
            for (int j = 0; j < 16; j += 4) {
                int k = kb + j;
                const float* s = xidx ? (arow + k)
                                      : ((k < Ksplit) ? (a0r + k) : (a1r + (k - Ksplit)));
                float4 v = *(const float4*)s;
                fa[j] = v.x; fa[j + 1] = v.y; fa[j + 2] = v.z; fa[j + 3] = v.w;
                float4 wv = *(const float4*)(wrow + k);
                fw[j] = wv.x; fw[j + 1] = wv.y; fw[j + 2] = wv.z; fw[j + 3] = wv.w;
            }
        } else {  // K tail (K=300): per-element mask, zero-pad
#pragma unroll
            for (int j = 0; j < 16; j++) {
                int k = kb + j;
                float av = 0.f, wv = 0.f;
                if (k < K) {
                    av = xidx ? arow[k] : ((k < Ksplit) ? a0r[k] : a1r[k - Ksplit]);
                    wv = wrow[k];
                }
                fa[j] = av; fw[j] = wv;
            }
        }
    };

    float fa[16], fw[16];
    LOADP(0, fa, fw);

    const int NP = (K + 31) >> 5;
    for (int kp = 0; kp < NP; kp++) {
        // split current panel regs -> bf16 hi/lo (thread-local, pre-barrier)
        s16x8 hA[2], lA[2], hW[2], lW[2];
#pragma unroll
        for (int c = 0; c < 2; c++) {
            split_pack8(fa + c * 8, hA[c], lA[c]);
            split_pack8(fw + c * 8, hW[c], lW[c]);
        }
        __syncthreads();  // previous panel's frag reads complete
#pragma unroll
        for (int c = 0; c < 2; c++) {
            int ch = (tid & 1) * 2 + c;
            int pch = ch ^ ((srow >> 1) & 3);
            int off = srow * 32 + pch * 8;
            *(s16x8*)&sAh[off] = hA[c];
            *(s16x8*)&sAl[off] = lA[c];
            *(s16x8*)&sWh[off] = hW[c];
            *(s16x8*)&sWl[off] = lW[c];
        }
        __syncthreads();

        if (kp + 1 < NP) LOADP(kp + 1, fa, fw);  // prefetch: hides under MFMA

        s16x8 ah[4], al[4];
#pragma unroll
        for (int m = 0; m < 4; m++) {
            int row = qm + m * 16 + fr;
            int off = row * 32 + ((fq ^ ((row >> 1) & 3)) * 8);
            ah[m] = *(const s16x8*)&sAh[off];
            al[m] = *(const s16x8*)&sAl[off];
        }
#pragma unroll
        for (int n = 0; n < 4; n++) {
            int row = qn + n * 16 + fr;
            int off = row * 32 + ((fq ^ ((row >> 1) & 3)) * 8);
            s16x8 bh = *(const s16x8*)&sWh[off];
            s16x8 bl = *(const s16x8*)&sWl[off];
#pragma unroll
            for (int m = 0; m < 4; m++) {
                acc[m][n] = __builtin_amdgcn_mfma_f32_16x16x32_bf16(ah[m], bh, acc[m][n], 0, 0, 0);
                acc[m][n] = __builtin_amdgcn_mfma_f32_16x16x32_bf16(ah[m], bl, acc[m][n], 0, 0, 0);
                acc[m][n] = __builtin_amdgcn_mfma_f32_16x16x32_bf16(al[m], bh, acc[m][n], 0, 0, 0);
            }
        }
    }

#pragma unroll
    for (int n = 0; n < 4; n++) {
        int gcol = bn * 128 + qn + n * 16 + fr;
        float b = bias[gcol];
#pragma unroll
        for (int m = 0; m < 4; m++) {
            int rbase = bm * 128 + qm + m * 16 + fq * 4;
#pragma unroll
            for (int r2 = 0; r2 < 4; r2++)
                C[(size_t)(rbase + r2) * N + gcol] = acc[m][n][r2] + b;
        }
    }
}

// ---------------- LSTM recurrent phase (r9, byte-for-byte) ----------------
// 64 blocks x 512 threads: dir = blk>>5, wg = blk&31 owns h[wg*16..+16).
// Thread (r=tid>>3, seg=tid&7): gate row grow=(r>>4)*512 + wg*16 + (r&15),
// k in [seg*64,+64). 64 Whh weights/thread in arch VGPRs. Pollers tid<62 spin on
// remote 32B h chunks (non-atomic sc0 sc1 dwordx4 pairs) until all 8 words pass
// the phase validity predicate, decode, drop into LDS. tid<16 computes gates,
// stores h (SYSTEM scope write-through, one coalesced wave-instr) and writes
// own LDS slice.
__global__ __attribute__((amdgpu_flat_work_group_size(512, 512), amdgpu_waves_per_eu(2, 2)))
void lstm_phase_k(const float* __restrict__ WxF,
                  const float* __restrict__ WxB,
                  const float* __restrict__ WhhF,
                  const float* __restrict__ WhhB,
                  float* __restrict__ histF,
                  float* __restrict__ histB,
                  int phase) {
    const int wg = blockIdx.x & 31;
    const int dir = blockIdx.x >> 5;
    const int tid = threadIdx.x;
    const float* Wx = dir ? WxB : WxF;
    const float* Whh = dir ? WhhB : WhhF;
    float* hist = dir ? histB : histF;
    const u32 ENC = phase ? 0x7F800000u : 0u;

    const int r = tid >> 3, seg = tid & 7;
    const int grow = (r >> 4) * 512 + wg * 16 + (r & 15);

    float w[64];
    {
        const float* wr = Whh + (size_t)grow * HH + seg * 64;
#pragma unroll
        for (int i = 0; i < 16; i++) {
            float4 v = *(const float4*)(wr + i * 4);
            w[i * 4 + 0] = v.x; w[i * 4 + 1] = v.y; w[i * 4 + 2] = v.z; w[i * 4 + 3] = v.w;
        }
    }

    // 32B-chunk index this thread polls (64 chunks of 8 floats; skip own wg's 2)
    const int j = (tid < 62) ? (tid + (tid >= wg * 2 ? 2 : 0)) : 0;

    __shared__ float lds_h[8 * 68];  // 8 seg-chunks of 64, stride 68
    __shared__ float lds_g[64];
    float c_state = 0.f;
    int capped = 0;

    for (int s = 0; s < TT; ++s) {
        const int t = dir ? (TT - 1 - s) : s;
        float wxv = 0.f;
        if (seg == 0) wxv = Wx[(size_t)t * NG + grow];  // prefetch, hidden behind poll

        if (s > 0) {
            const int tprev = dir ? (t + 1) : (t - 1);
            if (tid < 62) {
                const float* p = hist + (size_t)tprev * HH + j * 8;
                u32x4 v0, v1;
                if (!capped) {
                    int it = 0;
                    for (;;) {
                        ld_mall_b256(p, v0, v1);
                        bool ok;
                        if (phase) {
                            ok = ((v0.x & 0x7F800000u) >= 0x40000000u) &&
                                 ((v0.y & 0x7F800000u) >= 0x40000000u) &&
                                 ((v0.z & 0x7F800000u) >= 0x40000000u) &&
                                 ((v0.w & 0x7F800000u) >= 0x40000000u) &&
                                 ((v1.x & 0x7F800000u) >= 0x40000000u) &&
                                 ((v1.y & 0x7F800000u) >= 0x40000000u) &&
                                 ((v1.z & 0x7F800000u) >= 0x40000000u) &&
                                 ((v1.w & 0x7F800000u) >= 0x40000000u);
                        } else {
                            ok = (v0.x != 0xAAAAAAAAu) && (v0.y != 0xAAAAAAAAu) &&
                                 (v0.z != 0xAAAAAAAAu) && (v0.w != 0xAAAAAAAAu) &&
                                 (v1.x != 0xAAAAAAAAu) && (v1.y != 0xAAAAAAAAu) &&
                                 (v1.z != 0xAAAAAAAAu) && (v1.w != 0xAAAAAAAAu);
                        }
                        if (ok) break;
                        if (++it > (1 << 18)) { capped = 1; break; }  // sticky: never hang
                    }
                } else {
                    ld_mall_b256(p, v0, v1);
                }
                float* dst = &lds_h[(j >> 3) * 68 + ((j & 7) * 8)];
                float4 f0, f1;
                f0.x = __uint_as_float(v0.x ^ ENC); f0.y = __uint_as_float(v0.y ^ ENC);
                f0.z = __uint_as_float(v0.z ^ ENC); f0.w = __uint_as_float(v0.w ^ ENC);
                f1.x = __uint_as_float(v1.x ^ ENC); f1.y = __uint_as_float(v1.y ^ ENC);
                f1.z = __uint_as_float(v1.z ^ ENC); f1.w = __uint_as_float(v1.w ^ ENC);
                *(float4*)dst = f0;
                *(float4*)(dst + 4) = f1;
            }
            __syncthreads();
            float a0 = 0.f, a1 = 0.f, a2 = 0.f, a3 = 0.f;
            const float4* hv4 = (const float4*)&lds_h[seg * 68];
#pragma unroll
            for (int i = 0; i < 16; i++) {
                float4 hv = hv4[i];
                a0 += w[i * 4 + 0] * hv.x;
                a1 += w[i * 4 + 1] * hv.y;
                a2 += w[i * 4 + 2] * hv.z;
                a3 += w[i * 4 + 3] * hv.w;
            }
            float acc = (a0 + a1) + (a2 + a3);
            acc += __shfl_xor(acc, 1);
            acc += __shfl_xor(acc, 2);
            acc += __shfl_xor(acc, 4);
            if (seg == 0) lds_g[r] = acc + wxv;
        } else {
            if (seg == 0) lds_g[r] = wxv;
        }
        __syncthreads();

        if (tid < 16) {
            float gi = lds_g[tid], gf = lds_g[16 + tid], gg = lds_g[32 + tid], go = lds_g[48 + tid];
            float iv = sigm(gi), fv = sigm(gf), gv = tanh_(gg), ov = sigm(go);
            c_state = fv * c_state + iv * gv;
            float h = ov * tanh_(c_state);
            int hidx = wg * 16 + tid;
            lds_h[(hidx >> 6) * 68 + (hidx & 63)] = h;  // own slice for next step's dot
            st_sys_u32((u32*)&hist[(size_t)t * HH + hidx], __float_as_uint(h) ^ ENC);
        }
        // no end barrier: remote LDS slices are dead until the next poll barrier,
        // and lds_g is rewritten only after that barrier (which waits for tid<16).
    }
}

// ---------------- classifier + log_softmax (writes scores to d_out) ----------------
// hist holds phase-1 encoding: decode = xor 0x7F800000 per word.
__global__ __launch_bounds__(64, 4) void classifier_k(const float* __restrict__ histF,
                                                      const float* __restrict__ histB,
                                                      const float* __restrict__ Wc,
                                                      const float* __restrict__ bc,
                                                      float* __restrict__ outsc) {
    int t = blockIdx.x, lane = threadIdx.x;
    __shared__ float hrow[1024];
    const uint4* hf4 = (const uint4*)(histF + (size_t)t * HH);
    const uint4* hb4 = (const uint4*)(histB + (size_t)t * HH);
#pragma unroll
    for (int jj = 0; jj < 4; jj++) {
        int idx4 = jj * 64 + lane;  // 0..255 uint4s
        uint4 u = (idx4 < 128) ? hf4[idx4] : hb4[idx4 - 128];
        u.x ^= 0x7F800000u; u.y ^= 0x7F800000u; u.z ^= 0x7F800000u; u.w ^= 0x7F800000u;
        float4 v;
        v.x = __uint_as_float(u.x); v.y = __uint_as_float(u.y);
        v.z = __uint_as_float(u.z); v.w = __uint_as_float(u.w);
        *(float4*)&hrow[idx4 * 4] = v;
    }
    __syncthreads();
    float o = 0.f;
    if (lane < CC) {
        o = bc[lane];
        const float4* wr = (const float4*)(Wc + (size_t)lane * 1024);
#pragma unroll 4
        for (int kk = 0; kk < 256; ++kk) {
            float4 w4 = wr[kk];
            float4 h4 = *(const float4*)&hrow[kk * 4];
            o += w4.x * h4.x + w4.y * h4.y + w4.z * h4.z + w4.w * h4.w;
        }
    }
    float m = (lane < CC) ? o : -1e30f;
#pragma unroll
    for (int d = 1; d < 64; d <<= 1) m = fmaxf(m, __shfl_xor(m, d));
    float ex = (lane < CC) ? __expf(o - m) : 0.f;
#pragma unroll
    for (int d = 1; d < 64; d <<= 1) ex += __shfl_xor(ex, d);
    float lse = m + __logf(ex);
    if (lane < CC) outsc[(size_t)t * CC + lane] = o - lse;
}

// ---------------- viterbi forward + backtrack (single wave, shfl broadcast) ----------------
__global__ __launch_bounds__(64) void viterbi_k(const float* __restrict__ em,
                                               const float* __restrict__ trans,
                                               const float* __restrict__ startv,
                                               const float* __restrict__ endv,
                                               unsigned char* __restrict__ bp,
                                               float* __restrict__ outtags) {
    int lane = threadIdx.x;
    float tcol[CC];
#pragma unroll
    for (int p = 0; p < CC; p++) tcol[p] = 0.f;
    if (lane < CC) {
#pragma unroll
        for (int p = 0; p < CC; p++) tcol[p] = trans[p * CC + lane];  // trans[prev][next=lane]
    }
    float s = (lane < CC) ? (startv[lane] + em[lane]) : 0.f;

    for (int t = 1; t < TT; ++t) {
        float emv = (lane < CC) ? em[(size_t)t * CC + lane] : 0.f;
        float b0 = -1e30f, b1 = -1e30f;
        int i0 = 0, i1 = 20;
#pragma unroll
        for (int p = 0; p < 20; p++) {
            float c0 = __shfl(s, p) + tcol[p];
            float c1 = __shfl(s, p + 20) + tcol[p + 20];
            if (c0 > b0) { b0 = c0; i0 = p; }       // strict > = first-max
            if (c1 > b1) { b1 = c1; i1 = p + 20; }
        }
        float best = b0; int bi = i0;
        if (b1 > b0) { best = b1; bi = i1; }        // tie -> lower-index chain 0
        s = best + emv;
        if (lane < CC) bp[(size_t)t * CC + lane] = (unsigned char)bi;
    }
    float fv = (lane < CC) ? (s + endv[lane]) : -1e30f;
    int fi = (lane < CC) ? lane : 63;
#pragma unroll
    for (int d = 1; d < 64; d <<= 1) {
        float ov = __shfl_xor(fv, d);
        int oi = __shfl_xor(fi, d);
        if (ov > fv || (ov == fv && oi < fi)) { fv = ov; fi = oi; }
    }
    __threadfence();   // bp stores (lanes 0..39) visible to lane 0's loads
    if (lane == 0) {
        int cur = fi;
        outtags[TT - 1] = (float)cur;
        for (int t = TT - 2; t >= 0; --t) {
            cur = bp[(size_t)(t + 1) * CC + cur];
            outtags[t] = (float)cur;
        }
    }
}

extern "C" void kernel_launch(void* const* d_in, const int* in_sizes, int n_in,
                              void* d_out, int out_size, void* d_ws, size_t ws_size,
                              hipStream_t stream) {
    const int*   x     = (const int*)d_in[0];
    const float* emb   = (const float*)d_in[1];
    const float* Wih0f = (const float*)d_in[2];
    const float* Whh0f = (const float*)d_in[3];
    const float* b0f   = (const float*)d_in[4];
    const float* Wih0b = (const float*)d_in[5];
    const float* Whh0b = (const float*)d_in[6];
    const float* b0b   = (const float*)d_in[7];
    const float* Wih1f = (const float*)d_in[8];
    const float* Whh1f = (const float*)d_in[9];
    const float* b1f   = (const float*)d_in[10];
    const float* Wih1b = (const float*)d_in[11];
    const float* Whh1b = (const float*)d_in[12];
    const float* b1b   = (const float*)d_in[13];
    const float* Wc    = (const float*)d_in[14];
    const float* bc    = (const float*)d_in[15];
    const float* trans = (const float*)d_in[16];
    const float* startv= (const float*)d_in[17];
    const float* endv  = (const float*)d_in[18];

    char* ws = (char*)d_ws;
    // layout, total 84,148,224 B
    unsigned char* bp = (unsigned char*)(ws + 1024);       // 4096*40 = 163,840
    float* WxF  = (float*)(ws + 262144);                   // 4096*2048*4 = 33,554,432
    float* WxB  = (float*)(ws + 33816576);                 // 33,554,432
    float* histF= (float*)(ws + 67371008);                 // 4096*512*4 = 8,388,608
    float* histB= (float*)(ws + 75759616);                 // 8,388,608 -> 84,148,224

    if (ws_size < (size_t)84148224) return;  // diagnostic: zero output => ws too small

    float* out_sc   = (float*)d_out;                 // 4096*40 scores
    float* out_tags = out_sc + (size_t)TT * CC;      // 4096 tags (as float)

    // layer 0 input projections, F+B merged (emb gather fused into GEMM)
    gemm_bf16s_k<<<dim3(16, 32, 2), 256, 0, stream>>>(emb, nullptr, x,
                                                      Wih0f, b0f, WxF, Wih0b, b0b, WxB,
                                                      TT, NG, 300, 300);
    lstm_phase_k<<<64, 512, 0, stream>>>(WxF, WxB, Whh0f, Whh0b, histF, histB, 0);
    // layer 1 input projections, F+B merged (A = concat(histF, histB))
    gemm_bf16s_k<<<dim3(16, 32, 2), 256, 0, stream>>>(histF, histB, nullptr,
                                                      Wih1f, b1f, WxF, Wih1b, b1b, WxB,
                                                      TT, NG, 1024, 512);
    lstm_phase_k<<<64, 512, 0, stream>>>(WxF, WxB, Whh1f, Whh1b, histF, histB, 1);
    classifier_k<<<TT, 64, 0, stream>>>(histF, histB, Wc, bc, out_sc);
    viterbi_k<<<1, 64, 0, stream>>>(out_sc, trans, startv, endv, bp, out_tags);
}

// Round 8
// 16421.838 us; speedup vs baseline: 2.2209x; 1.0506x over previous
//
#include <hip/hip_runtime.h>

// BiLSTM-CRF tagger. V=100000 E=300 H=512 C=40 T=4096. ALL I/O float32.
// r14 = r13 (proven 17.25ms pass) + viterbi restructure (exact-math parallel):
//   - vit_fwd_k: 1-wave serial forward, SCORES ONLY (no bp): LDS-broadcast
//     s-row + 40 adds + 39-fmax TREE (max is exactly order-independent in
//     f32, so tree == reference value bit-exact); stores s-rows to ws.
//   - vit_chunk_k: 256 parallel blocks; chunk c recomputes bp for its 16
//     steps from stored s-rows with the reference's EXACT first-max scan
//     (bit-exact inputs => bit-exact bp), then builds per-exit-state path
//     tables (16 tags + entry state for each of 40 exits).
//   - vit_walk_k: 256 serial table lookups replace the 4094-step serial
//     pointer-chase backtrack.
//   Scratch (s_all, tbl, fi) reuses the dead WxF region (lstm-1 consumed it).
// r11/r13 lesson: pipelined reg-destination polling pays an ~RT drain at exit
//   (clobbered regs must be released) — cancels the detect gain; r6's simple
//   poll is near-optimal. Not retried.
// r10 lesson: append-only polled addresses + sc0sc1 (MALL) ops are the only
//   proven-safe sync combination.
// Sync scheme (r4..r9, proven): h words self-validate — phase 0 plain
//   (valid iff != 0xAAAAAAAA ws poison); phase 1 exp-flipped (^0x7F800000).

typedef unsigned int u32;
typedef unsigned long long u64;
typedef u32 u32x4 __attribute__((ext_vector_type(4)));
typedef __attribute__((ext_vector_type(8))) short s16x8;   // 8 bf16 (4 VGPRs)
typedef __attribute__((ext_vector_type(4))) float f32x4;

#define TT 4096
#define HH 512
#define CC 40
#define NG 2048  // 4*H gate rows

__device__ __forceinline__ float sigm(float x) { return 1.0f / (1.0f + __expf(-x)); }
__device__ __forceinline__ float tanh_(float x) { return 1.0f - 2.0f / (__expf(2.0f * x) + 1.0f); }

// system-scope write-through store: lands at MALL (the pollers' read point).
__device__ __forceinline__ void st_sys_u32(u32* p, u32 v) {
    asm volatile("global_store_dword %0, %1, off sc0 sc1"
                 :
                 : "v"(p), "v"(v)
                 : "memory");
}

// 32B system-scope-fresh load (bypass L1+L2, read at MALL).
__device__ __forceinline__ void ld_mall_b256(const float* p, u32x4& r0, u32x4& r1) {
    asm volatile(
        "global_load_dwordx4 %0, %2, off sc0 sc1\n\t"
        "global_load_dwordx4 %1, %2, off offset:16 sc0 sc1\n\t"
        "s_waitcnt vmcnt(0)"
        : "=&v"(r0), "=&v"(r1)
        : "v"(p)
        : "memory");
}

// ---------------- split-bf16 MFMA GEMM (pipelined): C = A @ W^T + bias ----------------
// (byte-for-byte r13 — proven)
__device__ __forceinline__ void split_pack8(const float* f, s16x8& hi, s16x8& lo) {
#pragma unroll
    for (int j = 0; j < 8; j++) {
        float x = f[j];
        u32 h = __float_as_uint(x) & 0xFFFF0000u;
        float hf = __uint_as_float(h);
        hi[j] = (short)(h >> 16);
        lo[j] = (short)(__float_as_uint(x - hf) >> 16);
    }
}

__global__ __launch_bounds__(256, 2) void gemm_bf16s_k(const float* __restrict__ A0,
                                                       const float* __restrict__ A1,
                                                       const int* __restrict__ xidx,
                                                       const float* __restrict__ W0,
                                                       const float* __restrict__ bias0,
                                                       float* __restrict__ C0,
                                                       const float* __restrict__ W1,
                                                       const float* __restrict__ bias1,
                                                       float* __restrict__ C1,
                                                       int M, int N, int K, int Ksplit) {
    __shared__ __align__(16) short sAh[128 * 32];
    __shared__ __align__(16) short sAl[128 * 32];
    __shared__ __align__(16) short sWh[128 * 32];
    __shared__ __align__(16) short sWl[128 * 32];
    const int tid = threadIdx.x;
    const int bn = blockIdx.x, bm = blockIdx.y;
    const float* W    = blockIdx.z ? W1 : W0;
    const float* bias = blockIdx.z ? bias1 : bias0;
    float*       C    = blockIdx.z ? C1 : C0;
    const int wid = tid >> 6, lane = tid & 63;
    const int qm = (wid >> 1) * 64, qn = (wid & 1) * 64;  // wave quadrant
    const int fr = lane & 15, fq = lane >> 4;             // frag free idx, k-group

    const int srow = tid >> 1;
    const int kh = (tid & 1) * 16;

    const int am = bm * 128 + srow;
    const float* arow = xidx ? (A0 + (size_t)xidx[am] * K) : nullptr;
    const float* a0r = xidx ? nullptr : (A0 + (size_t)am * Ksplit);
    const float* a1r = xidx ? nullptr : (A1 + (size_t)am * Ksplit);
    const float* wrow = W + (size_t)(bn * 128 + srow) * K;

    f32x4 acc[4][4] = {};

    auto LOADP = [&](int kp, float* fa, float* fw) {
        const int kb = kp * 32 + kh;
        if (kb + 16 <= K) {
#pragma unroll
            for (int j = 0; j < 16; j += 4) {
                int k = kb + j;
                const float* s = xidx ? (arow + k)
                                      : ((k < Ksplit) ? (a0r + k) : (a1r + (k - Ksplit)));
                float4 v = *(const float4*)s;
                fa[j] = v.x; fa[j + 1] = v.y; fa[j + 2] = v.z; fa[j + 3] = v.w;
                float4 wv = *(const float4*)(wrow + k);
                fw[j] = wv.x; fw[j + 1] = wv.y; fw[j + 2] = wv.z; fw[j + 3] = wv.w;
            }
        } else {
#pragma unroll
            for (int j = 0; j < 16; j++) {
                int k = kb + j;
                float av = 0.f, wv = 0.f;
                if (k < K) {
                    av = xidx ? arow[k] : ((k < Ksplit) ? a0r[k] : a1r[k - Ksplit]);
                    wv = wrow[k];
                }
                fa[j] = av; fw[j] = wv;
            }
        }
    };

    float fa[16], fw[16];
    LOADP(0, fa, fw);

    const int NP = (K + 31) >> 5;
    for (int kp = 0; kp < NP; kp++) {
        s16x8 hA[2], lA[2], hW[2], lW[2];
#pragma unroll
        for (int c = 0; c < 2; c++) {
            split_pack8(fa + c * 8, hA[c], lA[c]);
            split_pack8(fw + c * 8, hW[c], lW[c]);
        }
        __syncthreads();
#pragma unroll
        for (int c = 0; c < 2; c++) {
            int ch = (tid & 1) * 2 + c;
            int pch = ch ^ ((srow >> 1) & 3);
            int off = srow * 32 + pch * 8;
            *(s16x8*)&sAh[off] = hA[c];
            *(s16x8*)&sAl[off] = lA[c];
            *(s16x8*)&sWh[off] = hW[c];
            *(s16x8*)&sWl[off] = lW[c];
        }
        __syncthreads();

        if (kp + 1 < NP) LOADP(kp + 1, fa, fw);  // prefetch: hides under MFMA

        s16x8 ah[4], al[4];
#pragma unroll
        for (int m = 0; m < 4; m++) {
            int row = qm + m * 16 + fr;
            int off = row * 32 + ((fq ^ ((row >> 1) & 3)) * 8);
            ah[m] = *(const s16x8*)&sAh[off];
            al[m] = *(const s16x8*)&sAl[off];
        }
#pragma unroll
        for (int n = 0; n < 4; n++) {
            int row = qn + n * 16 + fr;
            int off = row * 32 + ((fq ^ ((row >> 1) & 3)) * 8);
            s16x8 bh = *(const s16x8*)&sWh[off];
            s16x8 bl = *(const s16x8*)&sWl[off];
#pragma unroll
            for (int m = 0; m < 4; m++) {
                acc[m][n] = __builtin_amdgcn_mfma_f32_16x16x32_bf16(ah[m], bh, acc[m][n], 0, 0, 0);
                acc[m][n] = __builtin_amdgcn_mfma_f32_16x16x32_bf16(ah[m], bl, acc[m][n], 0, 0, 0);
                acc[m][n] = __builtin_amdgcn_mfma_f32_16x16x32_bf16(al[m], bh, acc[m][n], 0, 0, 0);
            }
        }
    }

#pragma unroll
    for (int n = 0; n < 4; n++) {
        int gcol = bn * 128 + qn + n * 16 + fr;
        float b = bias[gcol];
#pragma unroll
        for (int m = 0; m < 4; m++) {
            int rbase = bm * 128 + qm + m * 16 + fq * 4;
#pragma unroll
            for (int r2 = 0; r2 < 4; r2++)
                C[(size_t)(rbase + r2) * N + gcol] = acc[m][n][r2] + b;
        }
    }
}

// ---------------- LSTM recurrent phase (r9, byte-for-byte) ----------------
__global__ __attribute__((amdgpu_flat_work_group_size(512, 512), amdgpu_waves_per_eu(2, 2)))
void lstm_phase_k(const float* __restrict__ WxF,
                  const float* __restrict__ WxB,
                  const float* __restrict__ WhhF,
                  const float* __restrict__ WhhB,
                  float* __restrict__ histF,
                  float* __restrict__ histB,
                  int phase) {
    const int wg = blockIdx.x & 31;
    const int dir = blockIdx.x >> 5;
    const int tid = threadIdx.x;
    const float* Wx = dir ? WxB : WxF;
    const float* Whh = dir ? WhhB : WhhF;
    float* hist = dir ? histB : histF;
    const u32 ENC = phase ? 0x7F800000u : 0u;

    const int r = tid >> 3, seg = tid & 7;
    const int grow = (r >> 4) * 512 + wg * 16 + (r & 15);

    float w[64];
    {
        const float* wr = Whh + (size_t)grow * HH + seg * 64;
#pragma unroll
        for (int i = 0; i < 16; i++) {
            float4 v = *(const float4*)(wr + i * 4);
            w[i * 4 + 0] = v.x; w[i * 4 + 1] = v.y; w[i * 4 + 2] = v.z; w[i * 4 + 3] = v.w;
        }
    }

    const int j = (tid < 62) ? (tid + (tid >= wg * 2 ? 2 : 0)) : 0;

    __shared__ float lds_h[8 * 68];  // 8 seg-chunks of 64, stride 68
    __shared__ float lds_g[64];
    float c_state = 0.f;
    int capped = 0;

    for (int s = 0; s < TT; ++s) {
        const int t = dir ? (TT - 1 - s) : s;
        float wxv = 0.f;
        if (seg == 0) wxv = Wx[(size_t)t * NG + grow];  // prefetch, hidden behind poll

        if (s > 0) {
            const int tprev = dir ? (t + 1) : (t - 1);
            if (tid < 62) {
                const float* p = hist + (size_t)tprev * HH + j * 8;
                u32x4 v0, v1;
                if (!capped) {
                    int it = 0;
                    for (;;) {
                        ld_mall_b256(p, v0, v1);
                        bool ok;
                        if (phase) {
                            ok = ((v0.x & 0x7F800000u) >= 0x40000000u) &&
                                 ((v0.y & 0x7F800000u) >= 0x40000000u) &&
                                 ((v0.z & 0x7F800000u) >= 0x40000000u) &&
                                 ((v0.w & 0x7F800000u) >= 0x40000000u) &&
                                 ((v1.x & 0x7F800000u) >= 0x40000000u) &&
                                 ((v1.y & 0x7F800000u) >= 0x40000000u) &&
                                 ((v1.z & 0x7F800000u) >= 0x40000000u) &&
                                 ((v1.w & 0x7F800000u) >= 0x40000000u);
                        } else {
                            ok = (v0.x != 0xAAAAAAAAu) && (v0.y != 0xAAAAAAAAu) &&
                                 (v0.z != 0xAAAAAAAAu) && (v0.w != 0xAAAAAAAAu) &&
                                 (v1.x != 0xAAAAAAAAu) && (v1.y != 0xAAAAAAAAu) &&
                                 (v1.z != 0xAAAAAAAAu) && (v1.w != 0xAAAAAAAAu);
                        }
                        if (ok) break;
                        if (++it > (1 << 18)) { capped = 1; break; }  // sticky: never hang
                    }
                } else {
                    ld_mall_b256(p, v0, v1);
                }
                float* dst = &lds_h[(j >> 3) * 68 + ((j & 7) * 8)];
                float4 f0, f1;
                f0.x = __uint_as_float(v0.x ^ ENC); f0.y = __uint_as_float(v0.y ^ ENC);
                f0.z = __uint_as_float(v0.z ^ ENC); f0.w = __uint_as_float(v0.w ^ ENC);
                f1.x = __uint_as_float(v1.x ^ ENC); f1.y = __uint_as_float(v1.y ^ ENC);
                f1.z = __uint_as_float(v1.z ^ ENC); f1.w = __uint_as_float(v1.w ^ ENC);
                *(float4*)dst = f0;
                *(float4*)(dst + 4) = f1;
            }
            __syncthreads();
            float a0 = 0.f, a1 = 0.f, a2 = 0.f, a3 = 0.f;
            const float4* hv4 = (const float4*)&lds_h[seg * 68];
#pragma unroll
            for (int i = 0; i < 16; i++) {
                float4 hv = hv4[i];
                a0 += w[i * 4 + 0] * hv.x;
                a1 += w[i * 4 + 1] * hv.y;
                a2 += w[i * 4 + 2] * hv.z;
                a3 += w[i * 4 + 3] * hv.w;
            }
            float acc = (a0 + a1) + (a2 + a3);
            acc += __shfl_xor(acc, 1);
            acc += __shfl_xor(acc, 2);
            acc += __shfl_xor(acc, 4);
            if (seg == 0) lds_g[r] = acc + wxv;
        } else {
            if (seg == 0) lds_g[r] = wxv;
        }
        __syncthreads();

        if (tid < 16) {
            float gi = lds_g[tid], gf = lds_g[16 + tid], gg = lds_g[32 + tid], go = lds_g[48 + tid];
            float iv = sigm(gi), fv = sigm(gf), gv = tanh_(gg), ov = sigm(go);
            c_state = fv * c_state + iv * gv;
            float h = ov * tanh_(c_state);
            int hidx = wg * 16 + tid;
            lds_h[(hidx >> 6) * 68 + (hidx & 63)] = h;  // own slice for next step's dot
            st_sys_u32((u32*)&hist[(size_t)t * HH + hidx], __float_as_uint(h) ^ ENC);
        }
    }
}

// ---------------- classifier + log_softmax (writes scores to d_out) ----------------
// hist holds phase-1 encoding: decode = xor 0x7F800000 per word.
__global__ __launch_bounds__(64, 4) void classifier_k(const float* __restrict__ histF,
                                                      const float* __restrict__ histB,
                                                      const float* __restrict__ Wc,
                                                      const float* __restrict__ bc,
                                                      float* __restrict__ outsc) {
    int t = blockIdx.x, lane = threadIdx.x;
    __shared__ float hrow[1024];
    const uint4* hf4 = (const uint4*)(histF + (size_t)t * HH);
    const uint4* hb4 = (const uint4*)(histB + (size_t)t * HH);
#pragma unroll
    for (int jj = 0; jj < 4; jj++) {
        int idx4 = jj * 64 + lane;  // 0..255 uint4s
        uint4 u = (idx4 < 128) ? hf4[idx4] : hb4[idx4 - 128];
        u.x ^= 0x7F800000u; u.y ^= 0x7F800000u; u.z ^= 0x7F800000u; u.w ^= 0x7F800000u;
        float4 v;
        v.x = __uint_as_float(u.x); v.y = __uint_as_float(u.y);
        v.z = __uint_as_float(u.z); v.w = __uint_as_float(u.w);
        *(float4*)&hrow[idx4 * 4] = v;
    }
    __syncthreads();
    float o = 0.f;
    if (lane < CC) {
        o = bc[lane];
        const float4* wr = (const float4*)(Wc + (size_t)lane * 1024);
#pragma unroll 4
        for (int kk = 0; kk < 256; ++kk) {
            float4 w4 = wr[kk];
            float4 h4 = *(const float4*)&hrow[kk * 4];
            o += w4.x * h4.x + w4.y * h4.y + w4.z * h4.z + w4.w * h4.w;
        }
    }
    float m = (lane < CC) ? o : -1e30f;
#pragma unroll
    for (int d = 1; d < 64; d <<= 1) m = fmaxf(m, __shfl_xor(m, d));
    float ex = (lane < CC) ? __expf(o - m) : 0.f;
#pragma unroll
    for (int d = 1; d < 64; d <<= 1) ex += __shfl_xor(ex, d);
    float lse = m + __logf(ex);
    if (lane < CC) outsc[(size_t)t * CC + lane] = o - lse;
}

// ---------------- viterbi stage 1: forward scores only (1 wave) ----------------
// s(t) = max_p(s(t-1)[p] + trans[p][next]) + em(t).  f32 max is exactly
// order-independent => fmax TREE produces bit-identical s to the reference
// scan. No bp tracking here (recomputed in parallel by vit_chunk_k).
__global__ __launch_bounds__(64) void vit_fwd_k(const float* __restrict__ em,
                                                const float* __restrict__ trans,
                                                const float* __restrict__ startv,
                                                const float* __restrict__ endv,
                                                float* __restrict__ s_all,
                                                u32* __restrict__ fi_out) {
    const int lane = threadIdx.x;
    float tcol[CC];
#pragma unroll
    for (int p = 0; p < CC; p++) tcol[p] = (lane < CC) ? trans[p * CC + lane] : -1e30f;
    __shared__ __align__(16) float srow[CC];
    float s = (lane < CC) ? (startv[lane] + em[lane]) : -1e30f;
    if (lane < CC) { s_all[lane] = s; srow[lane] = s; }
    float emv = (lane < CC) ? em[(size_t)1 * CC + lane] : 0.f;  // prefetch t=1
    for (int t = 1; t < TT; t++) {
        // candidates from srow = s(t-1) (single wave: lgkmcnt orders write->read)
        float c[CC];
        const float4* sr4 = (const float4*)srow;
#pragma unroll
        for (int q = 0; q < 10; q++) {
            float4 sv = sr4[q];
            c[q * 4 + 0] = sv.x + tcol[q * 4 + 0];
            c[q * 4 + 1] = sv.y + tcol[q * 4 + 1];
            c[q * 4 + 2] = sv.z + tcol[q * 4 + 2];
            c[q * 4 + 3] = sv.w + tcol[q * 4 + 3];
        }
        float emn = (t + 1 < TT && lane < CC) ? em[(size_t)(t + 1) * CC + lane] : 0.f;
        // exact max tree over 40 (order-independent)
#pragma unroll
        for (int i = 0; i < 20; i++) c[i] = fmaxf(c[i], c[i + 20]);
#pragma unroll
        for (int i = 0; i < 10; i++) c[i] = fmaxf(c[i], c[i + 10]);
#pragma unroll
        for (int i = 0; i < 5; i++) c[i] = fmaxf(c[i], c[i + 5]);
        float m = fmaxf(fmaxf(fmaxf(c[0], c[1]), fmaxf(c[2], c[3])), c[4]);
        s = m + emv;
        emv = emn;
        if (lane < CC) { srow[lane] = s; s_all[(size_t)t * CC + lane] = s; }
    }
    float fv = (lane < CC) ? (s + endv[lane]) : -1e30f;
    int fi = (lane < CC) ? lane : 63;
#pragma unroll
    for (int d = 1; d < 64; d <<= 1) {
        float ov = __shfl_xor(fv, d);
        int oi = __shfl_xor(fi, d);
        if (ov > fv || (ov == fv && oi < fi)) { fv = ov; fi = oi; }
    }
    if (lane == 0) fi_out[0] = (u32)fi;
}

// ---------------- viterbi stage 2: per-chunk bp + path tables (parallel) ----------------
// Chunk c covers t in [16c, 16c+16). Recomputes bp[t][next] =
// first-argmax_p(s(t-1)[p] + trans[p][next]) — EXACT reference scan order on
// bit-exact s — then builds, for each exit state e, the 16-tag path and the
// entry state. tbl row (5 u32): path packed 16x u8 + entry.
__global__ __launch_bounds__(64) void vit_chunk_k(const float* __restrict__ s_all,
                                                  const float* __restrict__ trans,
                                                  u32* __restrict__ tbl) {
    const int c = blockIdx.x, lane = threadIdx.x;
    const int tlo = c * 16;
    __shared__ float sld[16][CC];          // sld[i] = s(tlo + i - 1)
    __shared__ unsigned char bpl[16][CC];  // bpl[i] = bp[tlo + i]
    for (int idx = lane; idx < 16 * CC; idx += 64) {
        int row = idx / CC, col = idx % CC;
        int t = tlo - 1 + row;
        sld[row][col] = (t >= 0) ? s_all[(size_t)t * CC + col] : 0.f;
    }
    float tcol[CC];
#pragma unroll
    for (int p = 0; p < CC; p++) tcol[p] = (lane < CC) ? trans[p * CC + lane] : 0.f;
    __syncthreads();
    if (lane < CC) {
        for (int i = (c == 0 ? 1 : 0); i < 16; i++) {
            float b = -1e30f; int bi = 0;
#pragma unroll
            for (int p = 0; p < CC; p++) {
                float v = sld[i][p] + tcol[p];
                if (v > b) { b = v; bi = p; }  // strict > = first-max (reference)
            }
            bpl[i][lane] = (unsigned char)bi;
        }
    }
    __syncthreads();
    if (lane < CC) {
        unsigned char pth[16];
        int cur = lane;
        pth[15] = (unsigned char)cur;
        for (int i = 14; i >= 0; i--) { cur = bpl[i + 1][cur]; pth[i] = (unsigned char)cur; }
        u32 entry = (c > 0) ? (u32)bpl[0][cur] : 0u;
        u32* row = tbl + ((size_t)c * CC + lane) * 5;
#pragma unroll
        for (int q = 0; q < 4; q++)
            row[q] = (u32)pth[q * 4] | ((u32)pth[q * 4 + 1] << 8) |
                     ((u32)pth[q * 4 + 2] << 16) | ((u32)pth[q * 4 + 3] << 24);
        row[4] = entry;
    }
}

// ---------------- viterbi stage 3: chunk walk (256 serial lookups) ----------------
__global__ __launch_bounds__(64) void vit_walk_k(const u32* __restrict__ tbl,
                                                 const u32* __restrict__ fi_in,
                                                 float* __restrict__ outtags) {
    if (threadIdx.x != 0) return;
    int cur = (int)fi_in[0];
    for (int c = (TT / 16) - 1; c >= 0; c--) {
        const u32* row = tbl + ((size_t)c * CC + cur) * 5;
        u32 p0 = row[0], p1 = row[1], p2 = row[2], p3 = row[3];
        cur = (int)row[4];
        float* o = outtags + c * 16;
        o[0]  = (float)(p0 & 255); o[1]  = (float)((p0 >> 8) & 255);
        o[2]  = (float)((p0 >> 16) & 255); o[3]  = (float)(p0 >> 24);
        o[4]  = (float)(p1 & 255); o[5]  = (float)((p1 >> 8) & 255);
        o[6]  = (float)((p1 >> 16) & 255); o[7]  = (float)(p1 >> 24);
        o[8]  = (float)(p2 & 255); o[9]  = (float)((p2 >> 8) & 255);
        o[10] = (float)((p2 >> 16) & 255); o[11] = (float)(p2 >> 24);
        o[12] = (float)(p3 & 255); o[13] = (float)((p3 >> 8) & 255);
        o[14] = (float)((p3 >> 16) & 255); o[15] = (float)(p3 >> 24);
    }
}

extern "C" void kernel_launch(void* const* d_in, const int* in_sizes, int n_in,
                              void* d_out, int out_size, void* d_ws, size_t ws_size,
                              hipStream_t stream) {
    const int*   x     = (const int*)d_in[0];
    const float* emb   = (const float*)d_in[1];
    const float* Wih0f = (const float*)d_in[2];
    const float* Whh0f = (const float*)d_in[3];
    const float* b0f   = (const float*)d_in[4];
    const float* Wih0b = (const float*)d_in[5];
    const float* Whh0b = (const float*)d_in[6];
    const float* b0b   = (const float*)d_in[7];
    const float* Wih1f = (const float*)d_in[8];
    const float* Whh1f = (const float*)d_in[9];
    const float* b1f   = (const float*)d_in[10];
    const float* Wih1b = (const float*)d_in[11];
    const float* Whh1b = (const float*)d_in[12];
    const float* b1b   = (const float*)d_in[13];
    const float* Wc    = (const float*)d_in[14];
    const float* bc    = (const float*)d_in[15];
    const float* trans = (const float*)d_in[16];
    const float* startv= (const float*)d_in[17];
    const float* endv  = (const float*)d_in[18];

    char* ws = (char*)d_ws;
    // layout, total 84,148,224 B
    float* WxF  = (float*)(ws + 262144);                   // 4096*2048*4 = 33,554,432
    float* WxB  = (float*)(ws + 33816576);                 // 33,554,432
    float* histF= (float*)(ws + 67371008);                 // 4096*512*4 = 8,388,608
    float* histB= (float*)(ws + 75759616);                 // 8,388,608 -> 84,148,224
    // viterbi scratch reuses the WxF region (dead after lstm phase 1):
    float* s_all = (float*)(ws + 262144);                  // 4096*40*4 = 655,360
    u32*   vtbl  = (u32*)(ws + 262144 + 655360);           // 256*40*5*4 = 204,800
    u32*   fi_ws = (u32*)(ws + 262144 + 655360 + 204800);  // 4 B

    if (ws_size < (size_t)84148224) return;  // diagnostic: zero output => ws too small

    float* out_sc   = (float*)d_out;                 // 4096*40 scores
    float* out_tags = out_sc + (size_t)TT * CC;      // 4096 tags (as float)

    // layer 0 input projections, F+B merged (emb gather fused into GEMM)
    gemm_bf16s_k<<<dim3(16, 32, 2), 256, 0, stream>>>(emb, nullptr, x,
                                                      Wih0f, b0f, WxF, Wih0b, b0b, WxB,
                                                      TT, NG, 300, 300);
    lstm_phase_k<<<64, 512, 0, stream>>>(WxF, WxB, Whh0f, Whh0b, histF, histB, 0);
    // layer 1 input projections, F+B merged (A = concat(histF, histB))
    gemm_bf16s_k<<<dim3(16, 32, 2), 256, 0, stream>>>(histF, histB, nullptr,
                                                      Wih1f, b1f, WxF, Wih1b, b1b, WxB,
                                                      TT, NG, 1024, 512);
    lstm_phase_k<<<64, 512, 0, stream>>>(WxF, WxB, Whh1f, Whh1b, histF, histB, 1);
    classifier_k<<<TT, 64, 0, stream>>>(histF, histB, Wc, bc, out_sc);
    vit_fwd_k<<<1, 64, 0, stream>>>(out_sc, trans, startv, endv, s_all, fi_ws);
    vit_chunk_k<<<TT / 16, 64, 0, stream>>>(s_all, trans, vtbl);
    vit_walk_k<<<1, 64, 0, stream>>>(vtbl, fi_ws, out_tags);
}